// Round 7
// baseline (840.774 us; speedup 1.0000x reference)
//
#include <hip/hip_runtime.h>
#include <cstdint>

#define B_  128
#define S_  1024
#define U_  1024
#define IN_ 64

typedef unsigned short u16;
typedef __attribute__((ext_vector_type(8))) short short8v;
typedef __attribute__((ext_vector_type(4))) float f32x4;

__device__ __forceinline__ u16 f2bf(float f) {
  uint32_t u = __builtin_bit_cast(uint32_t, f);
  u += 0x7fffu + ((u >> 16) & 1u);
  return (u16)(u >> 16);
}
__device__ __forceinline__ float bf2f(u16 h) {
  uint32_t u = ((uint32_t)h) << 16;
  return __builtin_bit_cast(float, u);
}
// tanh via hw exp + rcp: ~6 VALU ops, |err| ~1e-5 (way under bf16 budget)
__device__ __forceinline__ float fast_tanh(float x) {
  float e = __expf(2.0f * x);
  return 1.0f - 2.0f * __builtin_amdgcn_rcpf(e + 1.0f);
}

// ---------------- enc f32 -> bf16 ----------------
__global__ void conv_enc_k(const float* __restrict__ in, u16* __restrict__ out) {
  size_t tid = (size_t)blockIdx.x * blockDim.x + threadIdx.x;
  size_t stride = (size_t)gridDim.x * blockDim.x;
  const size_t n8 = (size_t)B_ * S_ * U_ / 8;
  for (size_t p = tid; p < n8; p += stride) {
    const float* src = in + p * 8;
    float4 a = *(const float4*)src;
    float4 b = *(const float4*)(src + 4);
    short8v h;
    h[0] = (short)f2bf(a.x); h[1] = (short)f2bf(a.y);
    h[2] = (short)f2bf(a.z); h[3] = (short)f2bf(a.w);
    h[4] = (short)f2bf(b.x); h[5] = (short)f2bf(b.y);
    h[6] = (short)f2bf(b.z); h[7] = (short)f2bf(b.w);
    *(short8v*)(out + p * 8) = h;
  }
}

// ---------------- W1 (K x N) -> W1^T bf16 (N x K) ----------------
__global__ void conv_w1t_k(const float* __restrict__ W1, u16* __restrict__ w1t) {
  __shared__ float tile[32][33];
  int tx = threadIdx.x & 31, tg = threadIdx.x >> 5;  // 32 x 8
  int nb = blockIdx.x << 5, kb = blockIdx.y << 5;
#pragma unroll
  for (int i = 0; i < 4; ++i)
    tile[tg + i * 8][tx] = W1[(size_t)(kb + tg + i * 8) * U_ + nb + tx];
  __syncthreads();
#pragma unroll
  for (int i = 0; i < 4; ++i)
    w1t[(size_t)(nb + tg + i * 8) * U_ + kb + tx] = f2bf(tile[tx][tg + i * 8]);
}

// ---------------- fused score GEMM v6: 256x128 tile, 2 blocks/CU ----------
// score[r] = sum_n tanh( (enc @ W1)[r,n] + b1[n] + b2[n] + hb[b(r),n] ) * V[n]
// 4 waves (2M x 2N), per-wave 128x64 output (acc[8][4], 0.375 ds_read/MFMA),
// BK=32, 2 LDS buffers x 24KB (A 16KB + B 8KB) = 48KB -> 2 BLOCKS/CU
// (96KB LDS, ~200 regs < 256 -> 8 waves/CU = 2 waves/SIMD, one from each
// block: when block A stalls at a barrier/vmcnt, block B feeds the MFMA
// pipe — the barrier-skew cost of rounds 4-6's single-lockstep-block).
// 2 phases per K-tile t (cur = t&1):
//  ph1: ds_read A0-3+B(buf cur) [8]; STAGE all of t+1 -> buf cur^1 [6 loads];
//       s_barrier; lgkmcnt(0); sched_barrier; setprio(1); 16 MFMA (mi 0-3)
//  ph2: ds_read A4-7 [4]; vmcnt(0) [drains the 6 loads issued one full phase
//       earlier; residual latency covered by the co-resident block];
//       s_barrier; lgkmcnt(0); sched_barrier; setprio(1); 16 MFMA (mi 4-7)
// RAW: every wave's vmcnt(0) precedes its t.ph2 barrier -> all stage writes
//      of tile t+1 landed before any wave issues t+1.ph1 ds_reads.
// WAR: stage@t.ph1 overwrites regions last ds_read-issued before t-1.ph2's
//      barrier; stage write arrival trails by >=1 barrier + ~300cyc global
//      latency vs already-queued LDS reads.
// Swizzle: 16B-chunk c holds global chunk c ^ ((row>>1)&3); identical
// involution at stage-src (jsw) and read (cx); 2-way max aliasing = free.
__global__ __launch_bounds__(256, 2) void score_gemm3_k(
    const u16* __restrict__ encb, const u16* __restrict__ w1t,
    const float* __restrict__ hb, const float* __restrict__ b1,
    const float* __restrict__ b2, const float* __restrict__ Vv,
    float* __restrict__ score)
{
  __shared__ __align__(16) char lds[49152];    // 2 bufs x (A 16KB + B 8KB)
  const int tid  = threadIdx.x;
  const int lane = tid & 63;
  const int wid  = tid >> 6;                   // 0..3
  const int wm = wid >> 1, wn = wid & 1;
  const int r16 = lane & 15, g4 = lane >> 4;

  // XCD-aware bijective swizzle (4096 % 8 == 0), n-inner: the 8 N-tiles
  // sharing an A-panel land consecutively on one XCD -> A is 1 HBM fetch +
  // 7 L2 hits.
  int bid = blockIdx.x;
  int logical = (bid & 7) * 512 + (bid >> 3);
  const int row0 = (logical >> 3) << 8;        // M-tile * 256 (512 tiles)
  const int n0   = (logical & 7) << 7;         // N-tile * 128 (8 tiles)

  // read-side constants (row stride 64B = 32 bf16)
  const int cx   = (g4 ^ ((r16 >> 1) & 3)) << 4;     // swizzled 16B chunk
  const int arow = wm * 8192 + r16 * 64 + cx;        // + mi*1024, mi=0..7
  const int brow = 16384 + wn * 4096 + r16 * 64 + cx;// + ni*1024, ni=0..3

  // stage-side per-thread global base pointers (pre-swizzled source)
  const int jsw  = (tid & 3) ^ ((tid >> 3) & 3);
  const u16* pA  = encb + (((size_t)(row0 + (tid >> 2))) << 10) + jsw * 8;
  const u16* pB  = w1t  + (((size_t)(n0   + (tid >> 2))) << 10) + jsw * 8;

  f32x4 acc[8][4] = {};
  short8v bfr[4];

  // 6 global_load_lds per thread: A rows (tid>>2)+{0,64,128,192}, B rows
  // (tid>>2)+{0,64}. LDS dest chunk = i*256 + wid*64 + lane (linear).
#define STAGE6(KOFF) do {                                                      \
    const int _wb = _np + (wid << 10);                                         \
    _Pragma("unroll")                                                          \
    for (int i = 0; i < 4; ++i)                                                \
      __builtin_amdgcn_global_load_lds(                                        \
          (const __attribute__((address_space(1))) void*)(pA + (size_t)i * 65536 + (KOFF)), \
          (__attribute__((address_space(3))) void*)(lds + _wb + i * 4096), 16, 0, 0); \
    _Pragma("unroll")                                                          \
    for (int i = 0; i < 2; ++i)                                                \
      __builtin_amdgcn_global_load_lds(                                        \
          (const __attribute__((address_space(1))) void*)(pB + (size_t)i * 65536 + (KOFF)), \
          (__attribute__((address_space(3))) void*)(lds + _wb + 16384 + i * 4096), 16, 0, 0); \
  } while (0)

#define MFMA16(M2, AF) do {                                                    \
    __builtin_amdgcn_s_setprio(1);                                             \
    _Pragma("unroll")                                                          \
    for (int mi = 0; mi < 4; ++mi)                                             \
      _Pragma("unroll")                                                        \
      for (int ni = 0; ni < 4; ++ni)                                           \
        acc[(M2) * 4 + mi][ni] = __builtin_amdgcn_mfma_f32_16x16x32_bf16(      \
            (AF)[mi], bfr[ni], acc[(M2) * 4 + mi][ni], 0, 0, 0);               \
    __builtin_amdgcn_s_setprio(0);                                             \
  } while (0)

  // prologue: stage K-tile 0 into buf0, drain, barrier
  {
    const int _np = 0;
    STAGE6(0);
  }
  asm volatile("s_waitcnt vmcnt(0)" ::: "memory");
  __builtin_amdgcn_s_barrier();

  for (int t = 0; t < 32; ++t) {
    const int _pb = (t & 1) * 24576;
    const int _np = _pb ^ 24576;
    // ---- ph1 ----
    {
      short8v af[4];
      const char* _ab = lds + _pb;
#pragma unroll
      for (int mi = 0; mi < 4; ++mi)
        af[mi] = *(const short8v*)(_ab + arow + mi * 1024);
#pragma unroll
      for (int ni = 0; ni < 4; ++ni)
        bfr[ni] = *(const short8v*)(_ab + brow + ni * 1024);
      if (t < 31) { STAGE6((size_t)(t + 1) << 5); }
      __builtin_amdgcn_s_barrier();
      asm volatile("s_waitcnt lgkmcnt(0)" ::: "memory");
      __builtin_amdgcn_sched_barrier(0);
      MFMA16(0, af);
    }
    // ---- ph2 ----
    {
      short8v af[4];
      const char* _ab = lds + _pb;
#pragma unroll
      for (int mi = 0; mi < 4; ++mi)
        af[mi] = *(const short8v*)(_ab + arow + (4 + mi) * 1024);
      if (t < 31) asm volatile("s_waitcnt vmcnt(0)" ::: "memory");
      __builtin_amdgcn_s_barrier();
      asm volatile("s_waitcnt lgkmcnt(0)" ::: "memory");
      __builtin_amdgcn_sched_barrier(0);
      MFMA16(1, af);
    }
  }
#undef STAGE6
#undef MFMA16

  // ---- epilogue: tanh(+hb+b1+b2) * V, row-reduce over 16 lanes, atomicAdd ----
  const int b = row0 >> 10;                 // 256-row tile never crosses batch
  float vv[4], hbv[4];
#pragma unroll
  for (int ni = 0; ni < 4; ++ni) {
    int col = n0 + (wn << 6) + (ni << 4) + r16;
    vv[ni]  = Vv[col];
    hbv[ni] = hb[(b << 10) + col] + b1[col] + b2[col];
  }
  float rowsum[8][4];
#pragma unroll
  for (int mi = 0; mi < 8; ++mi)
#pragma unroll
    for (int j = 0; j < 4; ++j) rowsum[mi][j] = 0.0f;
#pragma unroll
  for (int mi = 0; mi < 8; ++mi)
#pragma unroll
    for (int ni = 0; ni < 4; ++ni)
#pragma unroll
      for (int j = 0; j < 4; ++j)
        rowsum[mi][j] += fast_tanh(acc[mi][ni][j] + hbv[ni]) * vv[ni];
#pragma unroll
  for (int mi = 0; mi < 8; ++mi)
#pragma unroll
    for (int j = 0; j < 4; ++j) {
      float rs = rowsum[mi][j];
      rs += __shfl_xor(rs, 1);
      rs += __shfl_xor(rs, 2);
      rs += __shfl_xor(rs, 4);
      rs += __shfl_xor(rs, 8);
      if (r16 == 0)
        atomicAdd(score + row0 + (wm << 7) + (mi << 4) + (g4 << 2) + j, rs);
    }
}

// ---------------- fallback fp32-input score GEMM (path B only) ----------------
__global__ __launch_bounds__(256) void score_gemm_f32_k(
    const float* __restrict__ encf, const u16* __restrict__ w1t,
    const float* __restrict__ hb, const float* __restrict__ b1,
    const float* __restrict__ b2, const float* __restrict__ Vv,
    float* __restrict__ score)
{
  __shared__ __align__(16) char lds[32768];
  const int tid  = threadIdx.x;
  const int lane = tid & 63;
  const int wid  = tid >> 6;
  const int wm = wid >> 1, wn = wid & 1;
  const int r16 = lane & 15, g4 = lane >> 4;
  int bid = blockIdx.x;
  int logical = (bid & 7) * 1024 + (bid >> 3);
  const int row0 = (logical >> 3) << 7;
  const int n0   = (logical & 7) << 7;
  f32x4 acc[4][4] = {};
  for (int kk = 0; kk < U_; kk += 64) {
#pragma unroll
    for (int qi = 0; qi < 4; ++qi) {
      int q = 16 + wid * 4 + qi;
      int n = ((q - 16) << 3) + (lane >> 3);
      int c = lane & 7;
      int j = c ^ (n & 7);
      const u16* src = w1t + (((size_t)(n0 + n)) << 10) + kk + (j << 3);
      __builtin_amdgcn_global_load_lds(
          (const __attribute__((address_space(1))) void*)src,
          (__attribute__((address_space(3))) void*)(lds + (q << 10)), 16, 0, 0);
    }
#pragma unroll
    for (int i = 0; i < 4; ++i) {
      int cg = tid * 4 + i;
      int r = cg >> 3, c = cg & 7;
      int j = c ^ (r & 7);
      const float* g = encf + (((size_t)(row0 + r)) << 10) + kk + (j << 3);
      float4 a = *(const float4*)g;
      float4 b = *(const float4*)(g + 4);
      short8v h;
      h[0] = (short)f2bf(a.x); h[1] = (short)f2bf(a.y);
      h[2] = (short)f2bf(a.z); h[3] = (short)f2bf(a.w);
      h[4] = (short)f2bf(b.x); h[5] = (short)f2bf(b.y);
      h[6] = (short)f2bf(b.z); h[7] = (short)f2bf(b.w);
      *(short8v*)(lds + (cg << 4)) = h;
    }
    __syncthreads();
#pragma unroll
    for (int ks = 0; ks < 2; ++ks) {
      short8v af[4], bf[4];
#pragma unroll
      for (int mi = 0; mi < 4; ++mi) {
        int row = (wm << 6) + (mi << 4) + r16;
        int jx = (ks << 2) + g4;
        af[mi] = *(const short8v*)(lds + (row << 7) + ((jx ^ (row & 7)) << 4));
      }
#pragma unroll
      for (int ni = 0; ni < 4; ++ni) {
        int n = (wn << 6) + (ni << 4) + r16;
        int jx = (ks << 2) + g4;
        bf[ni] = *(const short8v*)(lds + 16384 + (n << 7) + ((jx ^ (n & 7)) << 4));
      }
#pragma unroll
      for (int mi = 0; mi < 4; ++mi)
#pragma unroll
        for (int ni = 0; ni < 4; ++ni)
          acc[mi][ni] = __builtin_amdgcn_mfma_f32_16x16x32_bf16(af[mi], bf[ni], acc[mi][ni], 0, 0, 0);
    }
    __syncthreads();
  }
  const int b = row0 >> 10;
  float vv[4], hbv[4];
#pragma unroll
  for (int ni = 0; ni < 4; ++ni) {
    int col = n0 + (wn << 6) + (ni << 4) + r16;
    vv[ni]  = Vv[col];
    hbv[ni] = hb[(b << 10) + col] + b1[col] + b2[col];
  }
  float rowsum[4][4];
#pragma unroll
  for (int mi = 0; mi < 4; ++mi)
#pragma unroll
    for (int j = 0; j < 4; ++j) rowsum[mi][j] = 0.0f;
#pragma unroll
  for (int mi = 0; mi < 4; ++mi)
#pragma unroll
    for (int ni = 0; ni < 4; ++ni)
#pragma unroll
      for (int j = 0; j < 4; ++j)
        rowsum[mi][j] += fast_tanh(acc[mi][ni][j] + hbv[ni]) * vv[ni];
#pragma unroll
  for (int mi = 0; mi < 4; ++mi)
#pragma unroll
    for (int j = 0; j < 4; ++j) {
      float rs = rowsum[mi][j];
      rs += __shfl_xor(rs, 1);
      rs += __shfl_xor(rs, 2);
      rs += __shfl_xor(rs, 4);
      rs += __shfl_xor(rs, 8);
      if (r16 == 0)
        atomicAdd(score + row0 + (wm << 6) + (mi << 4) + (g4 << 2) + j, rs);
    }
}

// ---------------- softmax over S per batch ----------------
__global__ void softmax_k(const float* __restrict__ score, float* __restrict__ attn) {
  __shared__ float red[8];
  int b = blockIdx.x, t = threadIdx.x;     // 256 threads, 4 vals each
  float4 v = ((const float4*)(score + ((size_t)b << 10)))[t];
  float m = fmaxf(fmaxf(v.x, v.y), fmaxf(v.z, v.w));
  for (int o = 1; o < 64; o <<= 1) m = fmaxf(m, __shfl_xor(m, o));
  if ((t & 63) == 0) red[t >> 6] = m;
  __syncthreads();
  m = fmaxf(fmaxf(red[0], red[1]), fmaxf(red[2], red[3]));
  float e0 = expf(v.x - m), e1 = expf(v.y - m), e2 = expf(v.z - m), e3 = expf(v.w - m);
  float s = e0 + e1 + e2 + e3;
  for (int o = 1; o < 64; o <<= 1) s += __shfl_xor(s, o);
  if ((t & 63) == 0) red[4 + (t >> 6)] = s;
  __syncthreads();
  s = red[4] + red[5] + red[6] + red[7];
  float inv = 1.0f / s;
  float4 o4; o4.x = e0 * inv; o4.y = e1 * inv; o4.z = e2 * inv; o4.w = e3 * inv;
  ((float4*)(attn + ((size_t)b << 10)))[t] = o4;
}

// ---------------- context = attn^T @ enc  (accumulate into gin[:, :1024]) ----------------
template<bool ABF16>
__global__ void context_k(const void* __restrict__ encp, const float* __restrict__ attn,
                          float* __restrict__ gin) {
  __shared__ float aw[128];
  int b = blockIdx.x >> 3, sc = blockIdx.x & 7, t = threadIdx.x;
  if (t < 128) aw[t] = attn[((size_t)b << 10) + sc * 128 + t];
  __syncthreads();
  float a0 = 0.f, a1 = 0.f, a2 = 0.f, a3 = 0.f;
  size_t base = ((size_t)b << 20) + ((size_t)(sc * 128) << 10);
  for (int s = 0; s < 128; ++s) {
    float w = aw[s];
    if (ABF16) {
      ushort4 e = *(const ushort4*)((const u16*)encp + base + ((size_t)s << 10) + t * 4);
      a0 += w * bf2f(e.x); a1 += w * bf2f(e.y); a2 += w * bf2f(e.z); a3 += w * bf2f(e.w);
    } else {
      float4 e = *(const float4*)((const float*)encp + base + ((size_t)s << 10) + t * 4);
      a0 += w * e.x; a1 += w * e.y; a2 += w * e.z; a3 += w * e.w;
    }
  }
  float* g = gin + (size_t)b * 1088 + t * 4;
  atomicAdd(g + 0, a0); atomicAdd(g + 1, a1); atomicAdd(g + 2, a2); atomicAdd(g + 3, a3);
}

__global__ void ginx_k(const float* __restrict__ x, float* __restrict__ gin) {
  int i = blockIdx.x * 256 + threadIdx.x;   // 8192
  int b = i >> 6, c = i & 63;
  gin[(size_t)b * 1088 + 1024 + c] = x[i];
}

// ---------------- split-K fp32 GEMM: C += A@W (partial, atomic) ----------------
// 64x64 tile, K-chunk 64 per block (blockIdx.z), 256 threads, 4x4/thread.
__global__ __launch_bounds__(256) void gemm_splitk_k(
    const float* __restrict__ A, int lda,
    const float* __restrict__ W, int ldw,
    float* __restrict__ C, int ldc)
{
  __shared__ float As[64][68];
  __shared__ float Bs[64][64];
  int t = threadIdx.x;
  int m0 = blockIdx.x << 6, n0 = blockIdx.y << 6, k0 = blockIdx.z << 6;
#pragma unroll
  for (int q = 0; q < 4; ++q) {            // A: 64 rows x 16 float4
    int cidx = q * 256 + t;
    int m = cidx >> 4, c4 = cidx & 15;
    float4 v = *(const float4*)(A + (size_t)(m0 + m) * lda + k0 + (c4 << 2));
    As[m][(c4 << 2) + 0] = v.x; As[m][(c4 << 2) + 1] = v.y;
    As[m][(c4 << 2) + 2] = v.z; As[m][(c4 << 2) + 3] = v.w;
  }
#pragma unroll
  for (int q = 0; q < 4; ++q) {            // B: 64 k-rows x 16 float4
    int cidx = q * 256 + t;
    int k = cidx >> 4, nn = cidx & 15;
    *(float4*)&Bs[k][nn << 2] =
        *(const float4*)(W + (size_t)(k0 + k) * ldw + n0 + (nn << 2));
  }
  __syncthreads();
  int tx = t & 15, ty = t >> 4;
  float acc[4][4] = {};
#pragma unroll 8
  for (int k = 0; k < 64; ++k) {
    float a0 = As[(ty << 2) + 0][k], a1 = As[(ty << 2) + 1][k];
    float a2 = As[(ty << 2) + 2][k], a3 = As[(ty << 2) + 3][k];
    float4 bv = *(const float4*)&Bs[k][tx << 2];
    acc[0][0] += a0 * bv.x; acc[0][1] += a0 * bv.y; acc[0][2] += a0 * bv.z; acc[0][3] += a0 * bv.w;
    acc[1][0] += a1 * bv.x; acc[1][1] += a1 * bv.y; acc[1][2] += a1 * bv.z; acc[1][3] += a1 * bv.w;
    acc[2][0] += a2 * bv.x; acc[2][1] += a2 * bv.y; acc[2][2] += a2 * bv.z; acc[2][3] += a2 * bv.w;
    acc[3][0] += a3 * bv.x; acc[3][1] += a3 * bv.y; acc[3][2] += a3 * bv.z; acc[3][3] += a3 * bv.w;
  }
  int col = n0 + (tx << 2);
#pragma unroll
  for (int i = 0; i < 4; ++i) {
    int row = m0 + (ty << 2) + i;
#pragma unroll
    for (int j = 0; j < 4; ++j)
      atomicAdd(C + (size_t)row * ldc + col + j, acc[i][j]);
  }
}

// ---------------- GRU elementwise epilogues ----------------
__global__ void zr_k(const float* __restrict__ xg, const float* __restrict__ hr,
                     const float* __restrict__ hid, const float* __restrict__ bg,
                     float* __restrict__ z, float* __restrict__ rh) {
  int i = blockIdx.x * 256 + threadIdx.x;   // 131072
  int b = i >> 10, n = i & 1023;
  float zv = xg[(size_t)b * 3072 + n] + bg[n] + hr[(size_t)b * 2048 + n];
  float rv = xg[(size_t)b * 3072 + 1024 + n] + bg[1024 + n] + hr[(size_t)b * 2048 + 1024 + n];
  zv = 1.0f / (1.0f + expf(-zv));
  rv = 1.0f / (1.0f + expf(-rv));
  z[i] = zv;
  rh[i] = rv * hid[i];
}

__global__ void state_ep_k(const float* __restrict__ hh, const float* __restrict__ xg,
                           const float* __restrict__ bg, const float* __restrict__ z,
                           const float* __restrict__ hid, float* __restrict__ state) {
  int i = blockIdx.x * 256 + threadIdx.x;   // 131072
  int b = i >> 10, n = i & 1023;
  float val = hh[i] + xg[(size_t)b * 3072 + 2048 + n] + bg[2048 + n];
  float th = tanhf(val);
  float zv = z[i];
  state[i] = zv * hid[i] + (1.0f - zv) * th;
}

__global__ void out_ep_k(float* __restrict__ out, const float* __restrict__ bfc) {
  int i = blockIdx.x * 256 + threadIdx.x;   // 8192
  out[i] += bfc[i & 63];
}

extern "C" void kernel_launch(void* const* d_in, const int* in_sizes, int n_in,
                              void* d_out, int out_size, void* d_ws, size_t ws_size,
                              hipStream_t stream) {
  const float* x    = (const float*)d_in[0];
  const float* hid  = (const float*)d_in[1];
  const float* enc  = (const float*)d_in[2];
  const float* W1   = (const float*)d_in[3];
  const float* b1   = (const float*)d_in[4];
  const float* W2   = (const float*)d_in[5];
  const float* b2   = (const float*)d_in[6];
  const float* Vv   = (const float*)d_in[7];
  // d_in[8] = bV: softmax shift-invariant -> unused
  const float* Wk   = (const float*)d_in[9];
  const float* Wr   = (const float*)d_in[10];
  const float* bg   = (const float*)d_in[11];
  const float* Wfc  = (const float*)d_in[12];
  const float* bfc  = (const float*)d_in[13];

  float* out       = (float*)d_out;
  float* state_out = out + 8192;
  float* attn_out  = out + 8192 + 131072;

  char* ws = (char*)d_ws;
  u16*   w1t   = (u16*)(ws + 0);          // 2 MB
  // --- contiguous atomic-accumulator region (one memset) ---
  float* hb    = (float*)(ws + 2097152);  // 512 KB
  float* score = (float*)(ws + 2621440);  // 512 KB
  float* gin   = (float*)(ws + 3145728);  // 128*1088*4 = 544 KB
  float* xg    = (float*)(ws + 3702784);  // 1.5 MB
  float* hr    = (float*)(ws + 5275648);  // 1 MB
  float* hh    = (float*)(ws + 6324224);  // 512 KB
  // --- non-accumulated ---
  float* z     = (float*)(ws + 6848512);  // 512 KB
  float* rh    = (float*)(ws + 7372800);  // 512 KB
  u16*   enc16 = (u16*)(ws + 8388608);    // 256 MB (path A only)
  const bool pathA = ws_size >= (8388608ULL + 268435456ULL);

  hipMemsetAsync(ws + 2097152, 0, 6848512 - 2097152, stream);  // hb..hh
  hipMemsetAsync(out, 0, 32768, stream);                       // fc accumulator

  conv_w1t_k<<<dim3(32, 32), 256, 0, stream>>>(W1, w1t);
  if (pathA) conv_enc_k<<<4096, 256, 0, stream>>>(enc, enc16);

  // hb = hidden@W2 (biases folded into score epilogue)
  gemm_splitk_k<<<dim3(2, 16, 16), 256, 0, stream>>>(hid, 1024, W2, 1024, hb, 1024);

  if (pathA)
    score_gemm3_k<<<4096, 256, 0, stream>>>(enc16, w1t, hb, b1, b2, Vv, score);
  else
    score_gemm_f32_k<<<8192, 256, 0, stream>>>(enc, w1t, hb, b1, b2, Vv, score);

  softmax_k<<<128, 256, 0, stream>>>(score, attn_out);

  if (pathA) context_k<true><<<1024, 256, 0, stream>>>(enc16, attn_out, gin);
  else       context_k<false><<<1024, 256, 0, stream>>>(enc, attn_out, gin);
  ginx_k<<<32, 256, 0, stream>>>(x, gin);

  // xg = gin@Wk   (bg folded into zr_k / state_ep_k)
  gemm_splitk_k<<<dim3(2, 48, 17), 256, 0, stream>>>(gin, 1088, Wk, 3072, xg, 3072);
  // hr = hidden@Wr[:, :2048]
  gemm_splitk_k<<<dim3(2, 32, 16), 256, 0, stream>>>(hid, 1024, Wr, 3072, hr, 2048);
  zr_k<<<512, 256, 0, stream>>>(xg, hr, hid, bg, z, rh);
  // hh = (r*h)@Wr[:, 2U:]
  gemm_splitk_k<<<dim3(2, 16, 16), 256, 0, stream>>>(rh, 1024, Wr + 2048, 3072, hh, 1024);
  state_ep_k<<<512, 256, 0, stream>>>(hh, xg, bg, z, hid, state_out);
  // out = state@Wfc + bfc
  gemm_splitk_k<<<dim3(2, 1, 16), 256, 0, stream>>>(state_out, 1024, Wfc, 64, out, 64);
  out_ep_k<<<32, 256, 0, stream>>>(out, bfc);
}

// Round 10
// 830.319 us; speedup vs baseline: 1.0126x; 1.0126x over previous
//
#include <hip/hip_runtime.h>
#include <cstdint>

#define B_  128
#define S_  1024
#define U_  1024
#define IN_ 64

typedef unsigned short u16;
typedef __attribute__((ext_vector_type(8))) short short8v;
typedef __attribute__((ext_vector_type(4))) float f32x4;

__device__ __forceinline__ u16 f2bf(float f) {
  uint32_t u = __builtin_bit_cast(uint32_t, f);
  u += 0x7fffu + ((u >> 16) & 1u);
  return (u16)(u >> 16);
}
__device__ __forceinline__ float bf2f(u16 h) {
  uint32_t u = ((uint32_t)h) << 16;
  return __builtin_bit_cast(float, u);
}
// tanh via hw exp + rcp: ~6 VALU ops, |err| ~1e-5 (way under bf16 budget)
__device__ __forceinline__ float fast_tanh(float x) {
  float e = __expf(2.0f * x);
  return 1.0f - 2.0f * __builtin_amdgcn_rcpf(e + 1.0f);
}

__device__ __forceinline__ short8v pack8(float4 a, float4 b) {
  short8v h;
  h[0] = (short)f2bf(a.x); h[1] = (short)f2bf(a.y);
  h[2] = (short)f2bf(a.z); h[3] = (short)f2bf(a.w);
  h[4] = (short)f2bf(b.x); h[5] = (short)f2bf(b.y);
  h[6] = (short)f2bf(b.z); h[7] = (short)f2bf(b.w);
  return h;
}

// ---------------- W1 (K x N) -> W1^T bf16 (N x K) ----------------
__global__ void conv_w1t_k(const float* __restrict__ W1, u16* __restrict__ w1t) {
  __shared__ float tile[32][33];
  int tx = threadIdx.x & 31, tg = threadIdx.x >> 5;  // 32 x 8
  int nb = blockIdx.x << 5, kb = blockIdx.y << 5;
#pragma unroll
  for (int i = 0; i < 4; ++i)
    tile[tg + i * 8][tx] = W1[(size_t)(kb + tg + i * 8) * U_ + nb + tx];
  __syncthreads();
#pragma unroll
  for (int i = 0; i < 4; ++i)
    w1t[(size_t)(nb + tg + i * 8) * U_ + kb + tx] = f2bf(tile[tx][tg + i * 8]);
}

// ---------------- fused score GEMM v9: v8 + B-kh1 column-offset FIX ----------
// score[r] = sum_n tanh( (enc @ W1)[r,n] + b1[n] + b2[n] + hb[b(r),n] ) * V[n]
// Geometry = proven v5 (354us): 8 waves (2M x 4N), 256x256 tile, per-wave
// 128x64 (acc[8][4]), BK=64, 2 LDS buffers x 64KB (A-kh0|A-kh1|B-kh0|B-kh1),
// 4 phases/K-tile, ONE barrier per phase. A staged from f32 enc via regs.
// BUG FIXED (rounds 8-9, deterministic absmax 0.088): BSTAGE(KS, KOFF) uses
// KS only for the LDS dest; call sites passed KOFF=k1 for BOTH K-halves, so
// B-kh1 was filled with B-kh0's columns (A[k=32..64) * B[k=0..32)). v5's
// macro passed _kbase + KS*32. Fix: BSTAGE(1, k1 + 32) / prologue (1, 32).
// The identical absmax across rounds 8/9 proved determinism — the round-8
// "issue-order race" theory was wrong (the explicit vmcnt drains are kept
// as correct defense anyway):
//   ph2 before ACOMMIT: vmcnt(6)  [12 outstanding; drains all 6 of ph1 ->
//       rA0 ready, B0(t+1) landed, under any intra-phase issue order]
//   ph3 before ACOMMIT: vmcnt(0)  [drains ph2's 6 -> rA1 ready, B1 landed]
// RAW: every np-region commit >=1 barrier before its first reader.
// WAR: last readers lgkm-drained >=2 barriers before overwrite.
// Swizzle: LDS pos-chunk p of row r holds global chunk p ^ ((r>>1)&3);
// A: linear global read + swizzled ds_write dest; B: pre-swizzled global
// src + linear gload_lds dest; read side identical to v5 (verified: all
// row offsets wm*128/M2*64/mi*16/wn*64/ni*16 are 0 mod 8 -> (row>>1)&3
// depends only on r16).
__global__ __launch_bounds__(512, 1) void score_gemm4_k(
    const float* __restrict__ encf, const u16* __restrict__ w1t,
    const float* __restrict__ hb, const float* __restrict__ b1,
    const float* __restrict__ b2, const float* __restrict__ Vv,
    float* __restrict__ score)
{
  __shared__ __align__(16) char lds[131072];
  const int tid  = threadIdx.x;
  const int lane = tid & 63;
  const int wid  = tid >> 6;                   // 0..7
  const int wm = wid >> 2, wn = wid & 3;
  const int r16 = lane & 15, g4 = lane >> 4;

  // XCD-aware bijective swizzle (2048 % 8 == 0), n-inner for A-panel L2 reuse
  int bid = blockIdx.x;
  int logical = (bid & 7) * 256 + (bid >> 3);
  const int row0 = (logical >> 2) << 8;        // M-tile * 256
  const int n0   = (logical & 3) << 8;         // N-tile * 256

  // read-side constants
  const int cx   = (g4 ^ ((r16 >> 1) & 3)) << 4;     // swizzled 16B chunk
  const int arow = (wm * 128 + r16) * 64 + cx;       // + (M2*4+mi)*1024
  const int brow = (wn * 64  + r16) * 64 + cx;       // + ni*1024 (B region)

  // A staging: rows sr & sr+128, linear col chunk sc (8 f32); swizzled dest
  const int sr  = tid >> 2;
  const int sc  = tid & 3;
  const int sdst = sr * 64 + (((sc ^ ((sr >> 1) & 3))) << 4); // within A-half
  const float* pAf = encf + (((size_t)(row0 + sr)) << 10) + sc * 8;

  // B staging: pre-swizzled global source, linear gload_lds dest
  const int jsw  = (tid & 3) ^ ((tid >> 3) & 3);
  const u16* pB  = w1t + (((size_t)(n0 + sr)) << 10) + jsw * 8;

  f32x4 acc[8][4] = {};
  short8v bfr[4];
  float4 rA0a, rA0b, rA0c, rA0d;     // A half KS=0 in flight
  float4 rA1a, rA1b, rA1c, rA1d;     // A half KS=1 in flight

#define BSTAGE(KS, KOFF) do {                                                  \
    char* _wb = lds + _np + 32768 + (KS) * 16384 + (wid << 10);                \
    __builtin_amdgcn_global_load_lds(                                          \
        (const __attribute__((address_space(1))) void*)(pB + (KOFF)),          \
        (__attribute__((address_space(3))) void*)_wb, 16, 0, 0);               \
    __builtin_amdgcn_global_load_lds(                                          \
        (const __attribute__((address_space(1))) void*)(pB + 131072 + (KOFF)), \
        (__attribute__((address_space(3))) void*)(_wb + 8192), 16, 0, 0);      \
  } while (0)

#define AISSUE(Ra, Rb, Rc, Rd, KS, T1) do {                                    \
    const float* _s = pAf + (size_t)(T1) * 64 + (KS) * 32;                     \
    Ra = *(const float4*)_s;        Rb = *(const float4*)(_s + 4);             \
    Rc = *(const float4*)(_s + 131072); Rd = *(const float4*)(_s + 131076);    \
  } while (0)

#define ACOMMIT(Ra, Rb, Rc, Rd, KS) do {                                       \
    char* _d = lds + _np + (KS) * 16384 + sdst;                                \
    *(short8v*)_d          = pack8(Ra, Rb);                                    \
    *(short8v*)(_d + 8192) = pack8(Rc, Rd);                                    \
  } while (0)

#define RD_A(AF, M2, KS) do {                                                  \
    const char* _ab = lds + _pb + (KS) * 16384;                                \
    _Pragma("unroll")                                                          \
    for (int mi = 0; mi < 4; ++mi)                                             \
      (AF)[mi] = *(const short8v*)(_ab + arow + ((M2) * 4 + mi) * 1024);       \
  } while (0)

#define RD_B(KS) do {                                                          \
    const char* _bb = lds + _pb + 32768 + (KS) * 16384;                        \
    _Pragma("unroll")                                                          \
    for (int ni = 0; ni < 4; ++ni)                                             \
      bfr[ni] = *(const short8v*)(_bb + brow + ni * 1024);                     \
  } while (0)

#define MFMA16(M2, AF) do {                                                    \
    __builtin_amdgcn_s_setprio(1);                                             \
    _Pragma("unroll")                                                          \
    for (int mi = 0; mi < 4; ++mi)                                             \
      _Pragma("unroll")                                                        \
      for (int ni = 0; ni < 4; ++ni)                                           \
        acc[(M2) * 4 + mi][ni] = __builtin_amdgcn_mfma_f32_16x16x32_bf16(      \
            (AF)[mi], bfr[ni], acc[(M2) * 4 + mi][ni], 0, 0, 0);               \
    __builtin_amdgcn_s_setprio(0);                                             \
  } while (0)

#define LGKM0   asm volatile("s_waitcnt lgkmcnt(0)" ::: "memory")
#define VMC(N)  asm volatile("s_waitcnt vmcnt(" #N ")" ::: "memory")
#define SCHEDB  __builtin_amdgcn_sched_barrier(0)
#define BARRIER __builtin_amdgcn_s_barrier()

  // ---- prologue: stage K-tile 0 into buf0 ----
  {
    const int _np = 0;
    BSTAGE(0, 0); BSTAGE(1, 32);          // FIX: kh1 reads columns 32..64
    AISSUE(rA0a, rA0b, rA0c, rA0d, 0, 0);
    AISSUE(rA1a, rA1b, rA1c, rA1d, 1, 0);
    VMC(0);                               // all B gloads + rA drained
    ACOMMIT(rA0a, rA0b, rA0c, rA0d, 0);
    ACOMMIT(rA1a, rA1b, rA1c, rA1d, 1);
    LGKM0;
    BARRIER;
  }

  // ---- main loop: K-tiles 0..14 stage K-tile t+1 ----
  for (int t = 0; t < 15; ++t) {
    const int _pb = (t & 1) << 16;
    const int _np = _pb ^ 65536;
    const size_t k1 = (size_t)(t + 1) << 6;   // element col base of tile t+1
    short8v af[4];
    // ph1: issue 6 VMEM (BSTAGE(0)=2, rA0=4)
    RD_A(af, 0, 0); RD_B(0);
    BSTAGE(0, k1);
    AISSUE(rA0a, rA0b, rA0c, rA0d, 0, t + 1);
    BARRIER; LGKM0; SCHEDB;
    MFMA16(0, af);
    // ph2: issue 6 VMEM (BSTAGE(1)=2, rA1=4); 12 outstanding -> vmcnt(6)
    // drains ALL of ph1 (rA0 ready, B0(t+1) landed) under any issue order.
    RD_A(af, 1, 0);
    BSTAGE(1, k1 + 32);                   // FIX: kh1 reads columns +32
    AISSUE(rA1a, rA1b, rA1c, rA1d, 1, t + 1);
    VMC(6);
    ACOMMIT(rA0a, rA0b, rA0c, rA0d, 0);
    LGKM0; BARRIER; SCHEDB;
    MFMA16(1, af);
    // ph3: vmcnt(0) drains ph2's 6 (rA1 ready, B1(t+1) landed).
    RD_A(af, 0, 1); RD_B(1);
    VMC(0);
    ACOMMIT(rA1a, rA1b, rA1c, rA1d, 1);
    LGKM0; BARRIER; SCHEDB;
    MFMA16(0, af);
    // ph4
    RD_A(af, 1, 1);
    BARRIER; LGKM0; SCHEDB;
    MFMA16(1, af);
  }
  // ---- tail K-tile 15: no staging ----
  {
    const int _pb = (15 & 1) << 16;
    short8v af[4];
    RD_A(af, 0, 0); RD_B(0);
    BARRIER; LGKM0; SCHEDB;
    MFMA16(0, af);
    RD_A(af, 1, 0);
    BARRIER; LGKM0; SCHEDB;
    MFMA16(1, af);
    RD_A(af, 0, 1); RD_B(1);
    BARRIER; LGKM0; SCHEDB;
    MFMA16(0, af);
    RD_A(af, 1, 1);
    BARRIER; LGKM0; SCHEDB;
    MFMA16(1, af);
  }
#undef BSTAGE
#undef AISSUE
#undef ACOMMIT
#undef RD_A
#undef RD_B
#undef MFMA16
#undef LGKM0
#undef VMC
#undef SCHEDB
#undef BARRIER

  // ---- epilogue: tanh(+hb+b1+b2) * V, row-reduce over 16 lanes, atomicAdd ----
  const int b = row0 >> 10;                 // 256-row tile never crosses batch
  float vv[4], hbv[4];
#pragma unroll
  for (int ni = 0; ni < 4; ++ni) {
    int col = n0 + (wn << 6) + (ni << 4) + r16;
    vv[ni]  = Vv[col];
    hbv[ni] = hb[(b << 10) + col] + b1[col] + b2[col];
  }
  float rowsum[8][4];
#pragma unroll
  for (int mi = 0; mi < 8; ++mi)
#pragma unroll
    for (int j = 0; j < 4; ++j) rowsum[mi][j] = 0.0f;
#pragma unroll
  for (int mi = 0; mi < 8; ++mi)
#pragma unroll
    for (int ni = 0; ni < 4; ++ni)
#pragma unroll
      for (int j = 0; j < 4; ++j)
        rowsum[mi][j] += fast_tanh(acc[mi][ni][j] + hbv[ni]) * vv[ni];
#pragma unroll
  for (int mi = 0; mi < 8; ++mi)
#pragma unroll
    for (int j = 0; j < 4; ++j) {
      float rs = rowsum[mi][j];
      rs += __shfl_xor(rs, 1);
      rs += __shfl_xor(rs, 2);
      rs += __shfl_xor(rs, 4);
      rs += __shfl_xor(rs, 8);
      if (r16 == 0)
        atomicAdd(score + row0 + (wm << 7) + (mi << 4) + (g4 << 2) + j, rs);
    }
}

// ---------------- softmax over S per batch ----------------
__global__ void softmax_k(const float* __restrict__ score, float* __restrict__ attn) {
  __shared__ float red[8];
  int b = blockIdx.x, t = threadIdx.x;     // 256 threads, 4 vals each
  float4 v = ((const float4*)(score + ((size_t)b << 10)))[t];
  float m = fmaxf(fmaxf(v.x, v.y), fmaxf(v.z, v.w));
  for (int o = 1; o < 64; o <<= 1) m = fmaxf(m, __shfl_xor(m, o));
  if ((t & 63) == 0) red[t >> 6] = m;
  __syncthreads();
  m = fmaxf(fmaxf(red[0], red[1]), fmaxf(red[2], red[3]));
  float e0 = expf(v.x - m), e1 = expf(v.y - m), e2 = expf(v.z - m), e3 = expf(v.w - m);
  float s = e0 + e1 + e2 + e3;
  for (int o = 1; o < 64; o <<= 1) s += __shfl_xor(s, o);
  if ((t & 63) == 0) red[4 + (t >> 6)] = s;
  __syncthreads();
  s = red[4] + red[5] + red[6] + red[7];
  float inv = 1.0f / s;
  float4 o4; o4.x = e0 * inv; o4.y = e1 * inv; o4.z = e2 * inv; o4.w = e3 * inv;
  ((float4*)(attn + ((size_t)b << 10)))[t] = o4;
}

// ---------------- context = attn^T @ enc (f32), accumulate into gin ----------
__global__ void context_k(const float* __restrict__ encf, const float* __restrict__ attn,
                          float* __restrict__ gin) {
  __shared__ float aw[128];
  int b = blockIdx.x >> 3, sc = blockIdx.x & 7, t = threadIdx.x;
  if (t < 128) aw[t] = attn[((size_t)b << 10) + sc * 128 + t];
  __syncthreads();
  float a0 = 0.f, a1 = 0.f, a2 = 0.f, a3 = 0.f;
  size_t base = ((size_t)b << 20) + ((size_t)(sc * 128) << 10);
  for (int s = 0; s < 128; ++s) {
    float w = aw[s];
    float4 e = *(const float4*)(encf + base + ((size_t)s << 10) + t * 4);
    a0 += w * e.x; a1 += w * e.y; a2 += w * e.z; a3 += w * e.w;
  }
  float* g = gin + (size_t)b * 1088 + t * 4;
  atomicAdd(g + 0, a0); atomicAdd(g + 1, a1); atomicAdd(g + 2, a2); atomicAdd(g + 3, a3);
}

__global__ void ginx_k(const float* __restrict__ x, float* __restrict__ gin) {
  int i = blockIdx.x * 256 + threadIdx.x;   // 8192
  int b = i >> 6, c = i & 63;
  gin[(size_t)b * 1088 + 1024 + c] = x[i];
}

// ---------------- split-K fp32 GEMM: C += A@W (partial, atomic) ----------------
__global__ __launch_bounds__(256) void gemm_splitk_k(
    const float* __restrict__ A, int lda,
    const float* __restrict__ W, int ldw,
    float* __restrict__ C, int ldc)
{
  __shared__ float As[64][68];
  __shared__ float Bs[64][64];
  int t = threadIdx.x;
  int m0 = blockIdx.x << 6, n0 = blockIdx.y << 6, k0 = blockIdx.z << 6;
#pragma unroll
  for (int q = 0; q < 4; ++q) {            // A: 64 rows x 16 float4
    int cidx = q * 256 + t;
    int m = cidx >> 4, c4 = cidx & 15;
    float4 v = *(const float4*)(A + (size_t)(m0 + m) * lda + k0 + (c4 << 2));
    As[m][(c4 << 2) + 0] = v.x; As[m][(c4 << 2) + 1] = v.y;
    As[m][(c4 << 2) + 2] = v.z; As[m][(c4 << 2) + 3] = v.w;
  }
#pragma unroll
  for (int q = 0; q < 4; ++q) {            // B: 64 k-rows x 16 float4
    int cidx = q * 256 + t;
    int k = cidx >> 4, nn = cidx & 15;
    *(float4*)&Bs[k][nn << 2] =
        *(const float4*)(W + (size_t)(k0 + k) * ldw + n0 + (nn << 2));
  }
  __syncthreads();
  int tx = t & 15, ty = t >> 4;
  float acc[4][4] = {};
#pragma unroll 8
  for (int k = 0; k < 64; ++k) {
    float a0 = As[(ty << 2) + 0][k], a1 = As[(ty << 2) + 1][k];
    float a2 = As[(ty << 2) + 2][k], a3 = As[(ty << 2) + 3][k];
    float4 bv = *(const float4*)&Bs[k][tx << 2];
    acc[0][0] += a0 * bv.x; acc[0][1] += a0 * bv.y; acc[0][2] += a0 * bv.z; acc[0][3] += a0 * bv.w;
    acc[1][0] += a1 * bv.x; acc[1][1] += a1 * bv.y; acc[1][2] += a1 * bv.z; acc[1][3] += a1 * bv.w;
    acc[2][0] += a2 * bv.x; acc[2][1] += a2 * bv.y; acc[2][2] += a2 * bv.z; acc[2][3] += a2 * bv.w;
    acc[3][0] += a3 * bv.x; acc[3][1] += a3 * bv.y; acc[3][2] += a3 * bv.z; acc[3][3] += a3 * bv.w;
  }
  int col = n0 + (tx << 2);
#pragma unroll
  for (int i = 0; i < 4; ++i) {
    int row = m0 + (ty << 2) + i;
#pragma unroll
    for (int j = 0; j < 4; ++j)
      atomicAdd(C + (size_t)row * ldc + col + j, acc[i][j]);
  }
}

// ---------------- GRU elementwise epilogues ----------------
__global__ void zr_k(const float* __restrict__ xg, const float* __restrict__ hr,
                     const float* __restrict__ hid, const float* __restrict__ bg,
                     float* __restrict__ z, float* __restrict__ rh) {
  int i = blockIdx.x * 256 + threadIdx.x;   // 131072
  int b = i >> 10, n = i & 1023;
  float zv = xg[(size_t)b * 3072 + n] + bg[n] + hr[(size_t)b * 2048 + n];
  float rv = xg[(size_t)b * 3072 + 1024 + n] + bg[1024 + n] + hr[(size_t)b * 2048 + 1024 + n];
  zv = 1.0f / (1.0f + expf(-zv));
  rv = 1.0f / (1.0f + expf(-rv));
  z[i] = zv;
  rh[i] = rv * hid[i];
}

__global__ void state_ep_k(const float* __restrict__ hh, const float* __restrict__ xg,
                           const float* __restrict__ bg, const float* __restrict__ z,
                           const float* __restrict__ hid, float* __restrict__ state) {
  int i = blockIdx.x * 256 + threadIdx.x;   // 131072
  int b = i >> 10, n = i & 1023;
  float val = hh[i] + xg[(size_t)b * 3072 + 2048 + n] + bg[2048 + n];
  float th = tanhf(val);
  float zv = z[i];
  state[i] = zv * hid[i] + (1.0f - zv) * th;
}

__global__ void out_ep_k(float* __restrict__ out, const float* __restrict__ bfc) {
  int i = blockIdx.x * 256 + threadIdx.x;   // 8192
  out[i] += bfc[i & 63];
}

extern "C" void kernel_launch(void* const* d_in, const int* in_sizes, int n_in,
                              void* d_out, int out_size, void* d_ws, size_t ws_size,
                              hipStream_t stream) {
  const float* x    = (const float*)d_in[0];
  const float* hid  = (const float*)d_in[1];
  const float* enc  = (const float*)d_in[2];
  const float* W1   = (const float*)d_in[3];
  const float* b1   = (const float*)d_in[4];
  const float* W2   = (const float*)d_in[5];
  const float* b2   = (const float*)d_in[6];
  const float* Vv   = (const float*)d_in[7];
  // d_in[8] = bV: softmax shift-invariant -> unused
  const float* Wk   = (const float*)d_in[9];
  const float* Wr   = (const float*)d_in[10];
  const float* bg   = (const float*)d_in[11];
  const float* Wfc  = (const float*)d_in[12];
  const float* bfc  = (const float*)d_in[13];

  float* out       = (float*)d_out;
  float* state_out = out + 8192;
  float* attn_out  = out + 8192 + 131072;

  char* ws = (char*)d_ws;
  u16*   w1t   = (u16*)(ws + 0);          // 2 MB
  // --- contiguous atomic-accumulator region (one memset) ---
  float* hb    = (float*)(ws + 2097152);  // 512 KB
  float* score = (float*)(ws + 2621440);  // 512 KB
  float* gin   = (float*)(ws + 3145728);  // 128*1088*4 = 544 KB
  float* xg    = (float*)(ws + 3702784);  // 1.5 MB
  float* hr    = (float*)(ws + 5275648);  // 1 MB
  float* hh    = (float*)(ws + 6324224);  // 512 KB
  // --- non-accumulated ---
  float* z     = (float*)(ws + 6848512);  // 512 KB
  float* rh    = (float*)(ws + 7372800);  // 512 KB

  hipMemsetAsync(ws + 2097152, 0, 6848512 - 2097152, stream);  // hb..hh
  hipMemsetAsync(out, 0, 32768, stream);                       // fc accumulator

  conv_w1t_k<<<dim3(32, 32), 256, 0, stream>>>(W1, w1t);

  // hb = hidden@W2 (biases folded into score epilogue)
  gemm_splitk_k<<<dim3(2, 16, 16), 256, 0, stream>>>(hid, 1024, W2, 1024, hb, 1024);

  score_gemm4_k<<<2048, 512, 0, stream>>>(enc, w1t, hb, b1, b2, Vv, score);

  softmax_k<<<128, 256, 0, stream>>>(score, attn_out);

  context_k<<<1024, 256, 0, stream>>>(enc, attn_out, gin);
  ginx_k<<<32, 256, 0, stream>>>(x, gin);

  // xg = gin@Wk   (bg folded into zr_k / state_ep_k)
  gemm_splitk_k<<<dim3(2, 48, 17), 256, 0, stream>>>(gin, 1088, Wk, 3072, xg, 3072);
  // hr = hidden@Wr[:, :2048]
  gemm_splitk_k<<<dim3(2, 32, 16), 256, 0, stream>>>(hid, 1024, Wr, 3072, hr, 2048);
  zr_k<<<512, 256, 0, stream>>>(xg, hr, hid, bg, z, rh);
  // hh = (r*h)@Wr[:, 2U:]
  gemm_splitk_k<<<dim3(2, 16, 16), 256, 0, stream>>>(rh, 1024, Wr + 2048, 3072, hh, 1024);
  state_ep_k<<<512, 256, 0, stream>>>(hh, xg, bg, z, hid, state_out);
  // out = state@Wfc + bfc
  gemm_splitk_k<<<dim3(2, 1, 16), 256, 0, stream>>>(state_out, 1024, Wfc, 64, out, 64);
  out_ep_k<<<32, 256, 0, stream>>>(out, bfc);
}

// Round 11
// 782.332 us; speedup vs baseline: 1.0747x; 1.0613x over previous
//
#include <hip/hip_runtime.h>
#include <cstdint>

#define B_  128
#define S_  1024
#define U_  1024
#define IN_ 64

typedef unsigned short u16;
typedef __attribute__((ext_vector_type(8))) short short8v;
typedef __attribute__((ext_vector_type(4))) float f32x4;

__device__ __forceinline__ u16 f2bf(float f) {
  uint32_t u = __builtin_bit_cast(uint32_t, f);
  u += 0x7fffu + ((u >> 16) & 1u);
  return (u16)(u >> 16);
}
__device__ __forceinline__ float bf2f(u16 h) {
  uint32_t u = ((uint32_t)h) << 16;
  return __builtin_bit_cast(float, u);
}
// tanh via hw exp + rcp: ~6 VALU ops, |err| ~1e-5 (way under bf16 budget)
__device__ __forceinline__ float fast_tanh(float x) {
  float e = __expf(2.0f * x);
  return 1.0f - 2.0f * __builtin_amdgcn_rcpf(e + 1.0f);
}

__device__ __forceinline__ short8v pack8(float4 a, float4 b) {
  short8v h;
  h[0] = (short)f2bf(a.x); h[1] = (short)f2bf(a.y);
  h[2] = (short)f2bf(a.z); h[3] = (short)f2bf(a.w);
  h[4] = (short)f2bf(b.x); h[5] = (short)f2bf(b.y);
  h[6] = (short)f2bf(b.z); h[7] = (short)f2bf(b.w);
  return h;
}

// ---------------- enc f32 -> bf16 (64B/thread/iter) ----------------
__global__ void conv_enc_k(const float* __restrict__ in, u16* __restrict__ out) {
  size_t tid = (size_t)blockIdx.x * blockDim.x + threadIdx.x;
  size_t stride = (size_t)gridDim.x * blockDim.x;
  const size_t n16 = (size_t)B_ * S_ * U_ / 16;
  for (size_t p = tid; p < n16; p += stride) {
    const float* src = in + p * 16;
    float4 a = *(const float4*)src;
    float4 b = *(const float4*)(src + 4);
    float4 c = *(const float4*)(src + 8);
    float4 d = *(const float4*)(src + 12);
    *(short8v*)(out + p * 16)     = pack8(a, b);
    *(short8v*)(out + p * 16 + 8) = pack8(c, d);
  }
}

// ---------------- W1 (K x N) -> W1^T bf16 (N x K) ----------------
__global__ void conv_w1t_k(const float* __restrict__ W1, u16* __restrict__ w1t) {
  __shared__ float tile[32][33];
  int tx = threadIdx.x & 31, tg = threadIdx.x >> 5;  // 32 x 8
  int nb = blockIdx.x << 5, kb = blockIdx.y << 5;
#pragma unroll
  for (int i = 0; i < 4; ++i)
    tile[tg + i * 8][tx] = W1[(size_t)(kb + tg + i * 8) * U_ + nb + tx];
  __syncthreads();
#pragma unroll
  for (int i = 0; i < 4; ++i)
    w1t[(size_t)(nb + tg + i * 8) * U_ + kb + tx] = f2bf(tile[tx][tg + i * 8]);
}

// ---------------- fused score GEMM v5 (PROVEN 354us, round 6) ----
// score[r] = sum_n tanh( (enc @ W1)[r,n] + b1[n] + b2[n] + hb[b(r),n] ) * V[n]
// 8 waves (2M x 4N), per-wave 128x64 output, BK=64, 2 LDS double-buffers
// (2 x 64KB): A-kh0 | A-kh1 | B-kh0 | B-kh1, each 256x32 bf16 per buffer.
// 4 phases per K-tile, ONE barrier per phase:
//   [ds_read frags p] [stage 1 half of tile t+1] [vmcnt(4) at ph2,ph4]
//   [s_barrier] [lgkmcnt(0); sched_barrier] [setprio(1); 16 MFMA; setprio(0)]
// No trailing barrier: first wave done with its MFMA burst issues the next
// phase's ds_reads while others still feed the matrix pipe.
// RAW: A1B1(t) drained by stager's vmcnt(4)@t.ph2, read after t.ph3 barrier;
//   A0B0(t+1) drained @t.ph4, read after t+1.ph1 barrier. Never-0 vmcnt in
//   main loop (loads stay 2-3 phases in flight -> latency hidden).
// WAR: stage@t.ph1 overwrites region last ds_read at t-1.ph1, completed at
//   reader's lgkmcnt(0) pre-MFMA >=3 barriers earlier.
// Swizzle: 16B-chunk c holds global chunk c ^ ((row>>1)&3) (identical
// involution at stage-src (pre-swizzled global) and read; 2-way max = free,
// measured 0 conflicts).
// NOTE (r7-r10 lesson): fusing the f32->bf16 A-conversion into this kernel
// (register staging + vmcnt(0) drains) = 580us vs 354+150 split — doubled
// A-fetch bytes + 1-phase prefetch distance. Keep the split.
__global__ __launch_bounds__(512, 1) void score_gemm2_k(
    const u16* __restrict__ encb, const u16* __restrict__ w1t,
    const float* __restrict__ hb, const float* __restrict__ b1,
    const float* __restrict__ b2, const float* __restrict__ Vv,
    float* __restrict__ score)
{
  __shared__ __align__(16) char lds[131072];   // 2 bufs x (A 32KB + B 32KB)
  const int tid  = threadIdx.x;
  const int lane = tid & 63;
  const int wid  = tid >> 6;                   // 0..7
  const int wm = wid >> 2, wn = wid & 3;
  const int r16 = lane & 15, g4 = lane >> 4;

  // XCD-aware bijective swizzle (2048 % 8 == 0), n-inner for A-tile L2 reuse
  int bid = blockIdx.x;
  int logical = (bid & 7) * 256 + (bid >> 3);
  const int row0 = (logical >> 2) << 8;        // M-tile * 256
  const int n0   = (logical & 3) << 8;         // N-tile * 256

  // read-side constants
  const int cx   = (g4 ^ ((r16 >> 1) & 3)) << 4;     // swizzled 16B chunk
  const int arow = (wm * 128 + r16) * 64 + cx;       // + (M2*4+mi)*1024
  const int brow = (wn * 64  + r16) * 64 + cx;       // + ni*1024 (in B region)

  // stage-side per-thread global base pointers (pre-swizzled source)
  const int jsw  = (tid & 3) ^ ((tid >> 3) & 3);     // inverse-swizzled col chunk
  const u16* pA0 = encb + (((size_t)(row0 + (tid >> 2))) << 10) + jsw * 8;
  const u16* pA1 = pA0 + (size_t)128 * 1024;
  const u16* pB0 = w1t  + (((size_t)(n0   + (tid >> 2))) << 10) + jsw * 8;
  const u16* pB1 = pB0 + (size_t)128 * 1024;

  f32x4 acc[8][4] = {};
  short8v bfr[4];

#define STAGE(PTR0, PTR1, REGOFF, KOFF) do {                                   \
    const int _wb = _np + (REGOFF) + (wid << 10);                              \
    __builtin_amdgcn_global_load_lds(                                          \
        (const __attribute__((address_space(1))) void*)((PTR0) + (KOFF)),      \
        (__attribute__((address_space(3))) void*)(lds + _wb), 16, 0, 0);       \
    __builtin_amdgcn_global_load_lds(                                          \
        (const __attribute__((address_space(1))) void*)((PTR1) + (KOFF)),      \
        (__attribute__((address_space(3))) void*)(lds + _wb + 8192), 16, 0, 0);\
  } while (0)

  // PHASE: M2 = mi-half (0/1), KS = k-slice (0/1); stages half (SMAT,KS) of
  // K-tile t+1 when DO_STAGE; VM: -1 none, 4 -> vmcnt(4), 0 -> vmcnt(0).
#define PHASE(M2, KS, DO_STAGE, SPTR0, SPTR1, SREG, VM) do {                   \
    short8v af[4];                                                             \
    { const char* _ab = lds + _pb + (KS) * 16384;                              \
      _Pragma("unroll")                                                        \
      for (int mi = 0; mi < 4; ++mi)                                           \
        af[mi] = *(const short8v*)(_ab + arow + ((M2) * 4 + mi) * 1024); }     \
    if ((M2) == 0) {                                                           \
      const char* _bb = lds + _pb + 32768 + (KS) * 16384;                      \
      _Pragma("unroll")                                                        \
      for (int ni = 0; ni < 4; ++ni)                                           \
        bfr[ni] = *(const short8v*)(_bb + brow + ni * 1024); }                 \
    if (DO_STAGE) { STAGE(SPTR0, SPTR1, SREG, _kbase + (KS) * 32); }           \
    if ((VM) == 4)      asm volatile("s_waitcnt vmcnt(4)" ::: "memory");       \
    else if ((VM) == 0) asm volatile("s_waitcnt vmcnt(0)" ::: "memory");       \
    __builtin_amdgcn_s_barrier();                                              \
    asm volatile("s_waitcnt lgkmcnt(0)" ::: "memory");                         \
    __builtin_amdgcn_sched_barrier(0);                                         \
    __builtin_amdgcn_s_setprio(1);                                             \
    _Pragma("unroll")                                                          \
    for (int mi = 0; mi < 4; ++mi)                                             \
      _Pragma("unroll")                                                        \
      for (int ni = 0; ni < 4; ++ni)                                           \
        acc[(M2) * 4 + mi][ni] = __builtin_amdgcn_mfma_f32_16x16x32_bf16(      \
            af[mi], bfr[ni], acc[(M2) * 4 + mi][ni], 0, 0, 0);                 \
    __builtin_amdgcn_s_setprio(0);                                             \
  } while (0)

  // prologue: stage K-tile 0 (A0,B0,A1,B1) into buf0; drain A0,B0 (leave 4)
  {
    const int _np = 0;
    STAGE(pA0, pA1, 0,     0);
    STAGE(pB0, pB1, 32768, 0);
    STAGE(pA0, pA1, 16384, 32);
    STAGE(pB0, pB1, 49152, 32);
  }
  asm volatile("s_waitcnt vmcnt(4)" ::: "memory");
  __builtin_amdgcn_s_barrier();

  // main loop: K-tiles 0..14 stage K-tile t+1
  for (int t = 0; t < 15; ++t) {
    const int _pb = (t & 1) << 16;
    const int _np = _pb ^ 65536;
    const size_t _kbase = (size_t)(t + 1) << 6;         // element col of K-tile t+1
    PHASE(0, 0, 1, pA0, pA1, 0,     -1);
    PHASE(1, 0, 1, pB0, pB1, 32768,  4);
    PHASE(0, 1, 1, pA0, pA1, 16384, -1);
    PHASE(1, 1, 1, pB0, pB1, 49152,  4);
  }
  // tail K-tile 15: no staging; drain remaining A1(15),B1(15) before ph3
  {
    const int _pb = (15 & 1) << 16;
    const int _np = 0; const size_t _kbase = 0; (void)_np; (void)_kbase;
    PHASE(0, 0, 0, pA0, pA1, 0, -1);
    PHASE(1, 0, 0, pA0, pA1, 0,  0);
    PHASE(0, 1, 0, pA0, pA1, 0, -1);
    PHASE(1, 1, 0, pA0, pA1, 0, -1);
  }
#undef PHASE
#undef STAGE

  // ---- epilogue: tanh(+hb+b1+b2) * V, row-reduce over 16 lanes, atomicAdd ----
  const int b = row0 >> 10;                 // 256-row tile never crosses batch
  float vv[4], hbv[4];
#pragma unroll
  for (int ni = 0; ni < 4; ++ni) {
    int col = n0 + (wn << 6) + (ni << 4) + r16;
    vv[ni]  = Vv[col];
    hbv[ni] = hb[(b << 10) + col] + b1[col] + b2[col];
  }
  float rowsum[8][4];
#pragma unroll
  for (int mi = 0; mi < 8; ++mi)
#pragma unroll
    for (int j = 0; j < 4; ++j) rowsum[mi][j] = 0.0f;
#pragma unroll
  for (int mi = 0; mi < 8; ++mi)
#pragma unroll
    for (int ni = 0; ni < 4; ++ni)
#pragma unroll
      for (int j = 0; j < 4; ++j)
        rowsum[mi][j] += fast_tanh(acc[mi][ni][j] + hbv[ni]) * vv[ni];
#pragma unroll
  for (int mi = 0; mi < 8; ++mi)
#pragma unroll
    for (int j = 0; j < 4; ++j) {
      float rs = rowsum[mi][j];
      rs += __shfl_xor(rs, 1);
      rs += __shfl_xor(rs, 2);
      rs += __shfl_xor(rs, 4);
      rs += __shfl_xor(rs, 8);
      if (r16 == 0)
        atomicAdd(score + row0 + (wm << 7) + (mi << 4) + (g4 << 2) + j, rs);
    }
}

// ---------------- fallback fp32-input score GEMM (path B only) ----------------
__global__ __launch_bounds__(256) void score_gemm_f32_k(
    const float* __restrict__ encf, const u16* __restrict__ w1t,
    const float* __restrict__ hb, const float* __restrict__ b1,
    const float* __restrict__ b2, const float* __restrict__ Vv,
    float* __restrict__ score)
{
  __shared__ __align__(16) char lds[32768];
  const int tid  = threadIdx.x;
  const int lane = tid & 63;
  const int wid  = tid >> 6;
  const int wm = wid >> 1, wn = wid & 1;
  const int r16 = lane & 15, g4 = lane >> 4;
  int bid = blockIdx.x;
  int logical = (bid & 7) * 1024 + (bid >> 3);
  const int row0 = (logical >> 3) << 7;
  const int n0   = (logical & 7) << 7;
  f32x4 acc[4][4] = {};
  for (int kk = 0; kk < U_; kk += 64) {
#pragma unroll
    for (int qi = 0; qi < 4; ++qi) {
      int q = 16 + wid * 4 + qi;
      int n = ((q - 16) << 3) + (lane >> 3);
      int c = lane & 7;
      int j = c ^ (n & 7);
      const u16* src = w1t + (((size_t)(n0 + n)) << 10) + kk + (j << 3);
      __builtin_amdgcn_global_load_lds(
          (const __attribute__((address_space(1))) void*)src,
          (__attribute__((address_space(3))) void*)(lds + (q << 10)), 16, 0, 0);
    }
#pragma unroll
    for (int i = 0; i < 4; ++i) {
      int cg = tid * 4 + i;
      int r = cg >> 3, c = cg & 7;
      int j = c ^ (r & 7);
      const float* g = encf + (((size_t)(row0 + r)) << 10) + kk + (j << 3);
      float4 a = *(const float4*)g;
      float4 b = *(const float4*)(g + 4);
      *(short8v*)(lds + (cg << 4)) = pack8(a, b);
    }
    __syncthreads();
#pragma unroll
    for (int ks = 0; ks < 2; ++ks) {
      short8v af[4], bf[4];
#pragma unroll
      for (int mi = 0; mi < 4; ++mi) {
        int row = (wm << 6) + (mi << 4) + r16;
        int jx = (ks << 2) + g4;
        af[mi] = *(const short8v*)(lds + (row << 7) + ((jx ^ (row & 7)) << 4));
      }
#pragma unroll
      for (int ni = 0; ni < 4; ++ni) {
        int n = (wn << 6) + (ni << 4) + r16;
        int jx = (ks << 2) + g4;
        bf[ni] = *(const short8v*)(lds + 16384 + (n << 7) + ((jx ^ (n & 7)) << 4));
      }
#pragma unroll
      for (int mi = 0; mi < 4; ++mi)
#pragma unroll
        for (int ni = 0; ni < 4; ++ni)
          acc[mi][ni] = __builtin_amdgcn_mfma_f32_16x16x32_bf16(af[mi], bf[ni], acc[mi][ni], 0, 0, 0);
    }
    __syncthreads();
  }
  const int b = row0 >> 10;
  float vv[4], hbv[4];
#pragma unroll
  for (int ni = 0; ni < 4; ++ni) {
    int col = n0 + (wn << 6) + (ni << 4) + r16;
    vv[ni]  = Vv[col];
    hbv[ni] = hb[(b << 10) + col] + b1[col] + b2[col];
  }
  float rowsum[4][4];
#pragma unroll
  for (int mi = 0; mi < 4; ++mi)
#pragma unroll
    for (int j = 0; j < 4; ++j) rowsum[mi][j] = 0.0f;
#pragma unroll
  for (int mi = 0; mi < 4; ++mi)
#pragma unroll
    for (int ni = 0; ni < 4; ++ni)
#pragma unroll
      for (int j = 0; j < 4; ++j)
        rowsum[mi][j] += fast_tanh(acc[mi][ni][j] + hbv[ni]) * vv[ni];
#pragma unroll
  for (int mi = 0; mi < 4; ++mi)
#pragma unroll
    for (int j = 0; j < 4; ++j) {
      float rs = rowsum[mi][j];
      rs += __shfl_xor(rs, 1);
      rs += __shfl_xor(rs, 2);
      rs += __shfl_xor(rs, 4);
      rs += __shfl_xor(rs, 8);
      if (r16 == 0)
        atomicAdd(score + row0 + (wm << 6) + (mi << 4) + (g4 << 2) + j, rs);
    }
}

// ---------------- softmax over S per batch ----------------
__global__ void softmax_k(const float* __restrict__ score, float* __restrict__ attn) {
  __shared__ float red[8];
  int b = blockIdx.x, t = threadIdx.x;     // 256 threads, 4 vals each
  float4 v = ((const float4*)(score + ((size_t)b << 10)))[t];
  float m = fmaxf(fmaxf(v.x, v.y), fmaxf(v.z, v.w));
  for (int o = 1; o < 64; o <<= 1) m = fmaxf(m, __shfl_xor(m, o));
  if ((t & 63) == 0) red[t >> 6] = m;
  __syncthreads();
  m = fmaxf(fmaxf(red[0], red[1]), fmaxf(red[2], red[3]));
  float e0 = expf(v.x - m), e1 = expf(v.y - m), e2 = expf(v.z - m), e3 = expf(v.w - m);
  float s = e0 + e1 + e2 + e3;
  for (int o = 1; o < 64; o <<= 1) s += __shfl_xor(s, o);
  if ((t & 63) == 0) red[4 + (t >> 6)] = s;
  __syncthreads();
  s = red[4] + red[5] + red[6] + red[7];
  float inv = 1.0f / s;
  float4 o4; o4.x = e0 * inv; o4.y = e1 * inv; o4.z = e2 * inv; o4.w = e3 * inv;
  ((float4*)(attn + ((size_t)b << 10)))[t] = o4;
}

// ---------------- context = attn^T @ enc  (accumulate into gin[:, :1024]) ----------------
template<bool ABF16>
__global__ void context_k(const void* __restrict__ encp, const float* __restrict__ attn,
                          float* __restrict__ gin) {
  __shared__ float aw[128];
  int b = blockIdx.x >> 3, sc = blockIdx.x & 7, t = threadIdx.x;
  if (t < 128) aw[t] = attn[((size_t)b << 10) + sc * 128 + t];
  __syncthreads();
  float a0 = 0.f, a1 = 0.f, a2 = 0.f, a3 = 0.f;
  size_t base = ((size_t)b << 20) + ((size_t)(sc * 128) << 10);
  for (int s = 0; s < 128; ++s) {
    float w = aw[s];
    if (ABF16) {
      ushort4 e = *(const ushort4*)((const u16*)encp + base + ((size_t)s << 10) + t * 4);
      a0 += w * bf2f(e.x); a1 += w * bf2f(e.y); a2 += w * bf2f(e.z); a3 += w * bf2f(e.w);
    } else {
      float4 e = *(const float4*)((const float*)encp + base + ((size_t)s << 10) + t * 4);
      a0 += w * e.x; a1 += w * e.y; a2 += w * e.z; a3 += w * e.w;
    }
  }
  float* g = gin + (size_t)b * 1088 + t * 4;
  atomicAdd(g + 0, a0); atomicAdd(g + 1, a1); atomicAdd(g + 2, a2); atomicAdd(g + 3, a3);
}

__global__ void ginx_k(const float* __restrict__ x, float* __restrict__ gin) {
  int i = blockIdx.x * 256 + threadIdx.x;   // 8192
  int b = i >> 6, c = i & 63;
  gin[(size_t)b * 1088 + 1024 + c] = x[i];
}

// ---------------- split-K fp32 GEMM: C += A@W (partial, atomic) ----------------
__global__ __launch_bounds__(256) void gemm_splitk_k(
    const float* __restrict__ A, int lda,
    const float* __restrict__ W, int ldw,
    float* __restrict__ C, int ldc)
{
  __shared__ float As[64][68];
  __shared__ float Bs[64][64];
  int t = threadIdx.x;
  int m0 = blockIdx.x << 6, n0 = blockIdx.y << 6, k0 = blockIdx.z << 6;
#pragma unroll
  for (int q = 0; q < 4; ++q) {            // A: 64 rows x 16 float4
    int cidx = q * 256 + t;
    int m = cidx >> 4, c4 = cidx & 15;
    float4 v = *(const float4*)(A + (size_t)(m0 + m) * lda + k0 + (c4 << 2));
    As[m][(c4 << 2) + 0] = v.x; As[m][(c4 << 2) + 1] = v.y;
    As[m][(c4 << 2) + 2] = v.z; As[m][(c4 << 2) + 3] = v.w;
  }
#pragma unroll
  for (int q = 0; q < 4; ++q) {            // B: 64 k-rows x 16 float4
    int cidx = q * 256 + t;
    int k = cidx >> 4, nn = cidx & 15;
    *(float4*)&Bs[k][nn << 2] =
        *(const float4*)(W + (size_t)(k0 + k) * ldw + n0 + (nn << 2));
  }
  __syncthreads();
  int tx = t & 15, ty = t >> 4;
  float acc[4][4] = {};
#pragma unroll 8
  for (int k = 0; k < 64; ++k) {
    float a0 = As[(ty << 2) + 0][k], a1 = As[(ty << 2) + 1][k];
    float a2 = As[(ty << 2) + 2][k], a3 = As[(ty << 2) + 3][k];
    float4 bv = *(const float4*)&Bs[k][tx << 2];
    acc[0][0] += a0 * bv.x; acc[0][1] += a0 * bv.y; acc[0][2] += a0 * bv.z; acc[0][3] += a0 * bv.w;
    acc[1][0] += a1 * bv.x; acc[1][1] += a1 * bv.y; acc[1][2] += a1 * bv.z; acc[1][3] += a1 * bv.w;
    acc[2][0] += a2 * bv.x; acc[2][1] += a2 * bv.y; acc[2][2] += a2 * bv.z; acc[2][3] += a2 * bv.w;
    acc[3][0] += a3 * bv.x; acc[3][1] += a3 * bv.y; acc[3][2] += a3 * bv.z; acc[3][3] += a3 * bv.w;
  }
  int col = n0 + (tx << 2);
#pragma unroll
  for (int i = 0; i < 4; ++i) {
    int row = m0 + (ty << 2) + i;
#pragma unroll
    for (int j = 0; j < 4; ++j)
      atomicAdd(C + (size_t)row * ldc + col + j, acc[i][j]);
  }
}

// ---------------- GRU elementwise epilogues ----------------
__global__ void zr_k(const float* __restrict__ xg, const float* __restrict__ hr,
                     const float* __restrict__ hid, const float* __restrict__ bg,
                     float* __restrict__ z, float* __restrict__ rh) {
  int i = blockIdx.x * 256 + threadIdx.x;   // 131072
  int b = i >> 10, n = i & 1023;
  float zv = xg[(size_t)b * 3072 + n] + bg[n] + hr[(size_t)b * 2048 + n];
  float rv = xg[(size_t)b * 3072 + 1024 + n] + bg[1024 + n] + hr[(size_t)b * 2048 + 1024 + n];
  zv = 1.0f / (1.0f + expf(-zv));
  rv = 1.0f / (1.0f + expf(-rv));
  z[i] = zv;
  rh[i] = rv * hid[i];
}

__global__ void state_ep_k(const float* __restrict__ hh, const float* __restrict__ xg,
                           const float* __restrict__ bg, const float* __restrict__ z,
                           const float* __restrict__ hid, float* __restrict__ state) {
  int i = blockIdx.x * 256 + threadIdx.x;   // 131072
  int b = i >> 10, n = i & 1023;
  float val = hh[i] + xg[(size_t)b * 3072 + 2048 + n] + bg[2048 + n];
  float th = tanhf(val);
  float zv = z[i];
  state[i] = zv * hid[i] + (1.0f - zv) * th;
}

__global__ void out_ep_k(float* __restrict__ out, const float* __restrict__ bfc) {
  int i = blockIdx.x * 256 + threadIdx.x;   // 8192
  out[i] += bfc[i & 63];
}

extern "C" void kernel_launch(void* const* d_in, const int* in_sizes, int n_in,
                              void* d_out, int out_size, void* d_ws, size_t ws_size,
                              hipStream_t stream) {
  const float* x    = (const float*)d_in[0];
  const float* hid  = (const float*)d_in[1];
  const float* enc  = (const float*)d_in[2];
  const float* W1   = (const float*)d_in[3];
  const float* b1   = (const float*)d_in[4];
  const float* W2   = (const float*)d_in[5];
  const float* b2   = (const float*)d_in[6];
  const float* Vv   = (const float*)d_in[7];
  // d_in[8] = bV: softmax shift-invariant -> unused
  const float* Wk   = (const float*)d_in[9];
  const float* Wr   = (const float*)d_in[10];
  const float* bg   = (const float*)d_in[11];
  const float* Wfc  = (const float*)d_in[12];
  const float* bfc  = (const float*)d_in[13];

  float* out       = (float*)d_out;
  float* state_out = out + 8192;
  float* attn_out  = out + 8192 + 131072;

  char* ws = (char*)d_ws;
  u16*   w1t   = (u16*)(ws + 0);          // 2 MB
  // --- contiguous atomic-accumulator region (one memset) ---
  float* hb    = (float*)(ws + 2097152);  // 512 KB
  float* score = (float*)(ws + 2621440);  // 512 KB
  float* gin   = (float*)(ws + 3145728);  // 128*1088*4 = 544 KB
  float* xg    = (float*)(ws + 3702784);  // 1.5 MB
  float* hr    = (float*)(ws + 5275648);  // 1 MB
  float* hh    = (float*)(ws + 6324224);  // 512 KB
  // --- non-accumulated ---
  float* z     = (float*)(ws + 6848512);  // 512 KB
  float* rh    = (float*)(ws + 7372800);  // 512 KB
  u16*   enc16 = (u16*)(ws + 8388608);    // 256 MB (path A only)
  const bool pathA = ws_size >= (8388608ULL + 268435456ULL);

  hipMemsetAsync(ws + 2097152, 0, 6848512 - 2097152, stream);  // hb..hh
  hipMemsetAsync(out, 0, 32768, stream);                       // fc accumulator

  conv_w1t_k<<<dim3(32, 32), 256, 0, stream>>>(W1, w1t);
  if (pathA) conv_enc_k<<<4096, 256, 0, stream>>>(enc, enc16);

  // hb = hidden@W2 (biases folded into score epilogue)
  gemm_splitk_k<<<dim3(2, 16, 16), 256, 0, stream>>>(hid, 1024, W2, 1024, hb, 1024);

  if (pathA)
    score_gemm2_k<<<2048, 512, 0, stream>>>(enc16, w1t, hb, b1, b2, Vv, score);
  else
    score_gemm_f32_k<<<8192, 256, 0, stream>>>(enc, w1t, hb, b1, b2, Vv, score);

  softmax_k<<<128, 256, 0, stream>>>(score, attn_out);

  if (pathA) context_k<true><<<1024, 256, 0, stream>>>(enc16, attn_out, gin);
  else       context_k<false><<<1024, 256, 0, stream>>>(enc, attn_out, gin);
  ginx_k<<<32, 256, 0, stream>>>(x, gin);

  // xg = gin@Wk   (bg folded into zr_k / state_ep_k)
  gemm_splitk_k<<<dim3(2, 48, 17), 256, 0, stream>>>(gin, 1088, Wk, 3072, xg, 3072);
  // hr = hidden@Wr[:, :2048]
  gemm_splitk_k<<<dim3(2, 32, 16), 256, 0, stream>>>(hid, 1024, Wr, 3072, hr, 2048);
  zr_k<<<512, 256, 0, stream>>>(xg, hr, hid, bg, z, rh);
  // hh = (r*h)@Wr[:, 2U:]
  gemm_splitk_k<<<dim3(2, 16, 16), 256, 0, stream>>>(rh, 1024, Wr + 2048, 3072, hh, 1024);
  state_ep_k<<<512, 256, 0, stream>>>(hh, xg, bg, z, hid, state_out);
  // out = state@Wfc + bfc
  gemm_splitk_k<<<dim3(2, 1, 16), 256, 0, stream>>>(state_out, 1024, Wfc, 64, out, 64);
  out_ep_k<<<32, 256, 0, stream>>>(out, bfc);
}

// Round 12
// 772.636 us; speedup vs baseline: 1.0882x; 1.0125x over previous
//
#include <hip/hip_runtime.h>
#include <cstdint>

#define B_  128
#define S_  1024
#define U_  1024
#define IN_ 64

typedef unsigned short u16;
typedef __attribute__((ext_vector_type(8))) short short8v;
typedef __attribute__((ext_vector_type(4))) float f32x4;

__device__ __forceinline__ u16 f2bf(float f) {
  uint32_t u = __builtin_bit_cast(uint32_t, f);
  u += 0x7fffu + ((u >> 16) & 1u);
  return (u16)(u >> 16);
}
__device__ __forceinline__ float bf2f(u16 h) {
  uint32_t u = ((uint32_t)h) << 16;
  return __builtin_bit_cast(float, u);
}
// tanh via hw exp + rcp: ~6 VALU ops, |err| ~1e-5 (way under bf16 budget)
__device__ __forceinline__ float fast_tanh(float x) {
  float e = __expf(2.0f * x);
  return 1.0f - 2.0f * __builtin_amdgcn_rcpf(e + 1.0f);
}

__device__ __forceinline__ short8v pack8(float4 a, float4 b) {
  short8v h;
  h[0] = (short)f2bf(a.x); h[1] = (short)f2bf(a.y);
  h[2] = (short)f2bf(a.z); h[3] = (short)f2bf(a.w);
  h[4] = (short)f2bf(b.x); h[5] = (short)f2bf(b.y);
  h[6] = (short)f2bf(b.z); h[7] = (short)f2bf(b.w);
  return h;
}

// ---------------- fused prep: conv_w1t (blocks 0..1023) + conv_enc (rest) ----
// Independent outputs (w1t vs enc16); w1t blocks first so they overlap under
// conv_enc's HBM stream instead of serializing as a separate dispatch.
__global__ __launch_bounds__(256) void prep_k(
    const float* __restrict__ W1, u16* __restrict__ w1t,
    const float* __restrict__ enc, u16* __restrict__ enc16) {
  int bx = blockIdx.x;
  if (bx < 1024) {
    // W1 (K x N) -> W1^T bf16 (N x K), 32x32 tile per block
    __shared__ float tile[32][33];
    int tx = threadIdx.x & 31, tg = threadIdx.x >> 5;  // 32 x 8
    int nb = (bx & 31) << 5, kb = (bx >> 5) << 5;
#pragma unroll
    for (int i = 0; i < 4; ++i)
      tile[tg + i * 8][tx] = W1[(size_t)(kb + tg + i * 8) * U_ + nb + tx];
    __syncthreads();
#pragma unroll
    for (int i = 0; i < 4; ++i)
      w1t[(size_t)(nb + tg + i * 8) * U_ + kb + tx] = f2bf(tile[tx][tg + i * 8]);
  } else if (enc16) {
    // enc f32 -> bf16, 64B/thread/iter grid-stride
    size_t tid = (size_t)(bx - 1024) * 256 + threadIdx.x;
    size_t stride = (size_t)(gridDim.x - 1024) * 256;
    const size_t n16 = (size_t)B_ * S_ * U_ / 16;
    for (size_t p = tid; p < n16; p += stride) {
      const float* src = enc + p * 16;
      float4 a = *(const float4*)src;
      float4 b = *(const float4*)(src + 4);
      float4 c = *(const float4*)(src + 8);
      float4 d = *(const float4*)(src + 12);
      *(short8v*)(enc16 + p * 16)     = pack8(a, b);
      *(short8v*)(enc16 + p * 16 + 8) = pack8(c, d);
    }
  }
}

// ---------------- fused score GEMM v5 (PROVEN ~360us; DO NOT RESTRUCTURE) ----
// score[r] = sum_n tanh( (enc @ W1)[r,n] + b1[n] + b2[n] + hb[b(r),n] ) * V[n]
// 8 waves (2M x 4N), per-wave 128x64 output, BK=64, 2 LDS double-buffers
// (2 x 64KB): A-kh0 | A-kh1 | B-kh0 | B-kh1, each 256x32 bf16 per buffer.
// 4 phases per K-tile, ONE barrier per phase:
//   [ds_read frags p] [stage 1 half of tile t+1] [vmcnt(4) at ph2,ph4]
//   [s_barrier] [lgkmcnt(0); sched_barrier] [setprio(1); 16 MFMA; setprio(0)]
// Bracketing history: v4 frag-dbuf neutral; v6 2-blocks/CU -20%; v7-v10
// fused-f32 A-staging -60% (double fetch + 1-phase prefetch distance).
// RAW: A1B1(t) drained by stager's vmcnt(4)@t.ph2, read after t.ph3 barrier;
//   A0B0(t+1) drained @t.ph4, read after t+1.ph1 barrier. Never-0 vmcnt in
//   main loop. WAR: stage@t.ph1 overwrites region last read at t-1.ph1,
//   completed >=3 barriers earlier.
// Swizzle: 16B-chunk c holds global chunk c ^ ((row>>1)&3), same involution
// at stage-src (pre-swizzled global) and read; measured 0 bank conflicts.
__global__ __launch_bounds__(512, 1) void score_gemm2_k(
    const u16* __restrict__ encb, const u16* __restrict__ w1t,
    const float* __restrict__ hb, const float* __restrict__ b1,
    const float* __restrict__ b2, const float* __restrict__ Vv,
    float* __restrict__ score)
{
  __shared__ __align__(16) char lds[131072];   // 2 bufs x (A 32KB + B 32KB)
  const int tid  = threadIdx.x;
  const int lane = tid & 63;
  const int wid  = tid >> 6;                   // 0..7
  const int wm = wid >> 2, wn = wid & 3;
  const int r16 = lane & 15, g4 = lane >> 4;

  // XCD-aware bijective swizzle (2048 % 8 == 0), n-inner for A-tile L2 reuse
  int bid = blockIdx.x;
  int logical = (bid & 7) * 256 + (bid >> 3);
  const int row0 = (logical >> 2) << 8;        // M-tile * 256
  const int n0   = (logical & 3) << 8;         // N-tile * 256

  // read-side constants
  const int cx   = (g4 ^ ((r16 >> 1) & 3)) << 4;     // swizzled 16B chunk
  const int arow = (wm * 128 + r16) * 64 + cx;       // + (M2*4+mi)*1024
  const int brow = (wn * 64  + r16) * 64 + cx;       // + ni*1024 (in B region)

  // stage-side per-thread global base pointers (pre-swizzled source)
  const int jsw  = (tid & 3) ^ ((tid >> 3) & 3);     // inverse-swizzled col chunk
  const u16* pA0 = encb + (((size_t)(row0 + (tid >> 2))) << 10) + jsw * 8;
  const u16* pA1 = pA0 + (size_t)128 * 1024;
  const u16* pB0 = w1t  + (((size_t)(n0   + (tid >> 2))) << 10) + jsw * 8;
  const u16* pB1 = pB0 + (size_t)128 * 1024;

  f32x4 acc[8][4] = {};
  short8v bfr[4];

#define STAGE(PTR0, PTR1, REGOFF, KOFF) do {                                   \
    const int _wb = _np + (REGOFF) + (wid << 10);                              \
    __builtin_amdgcn_global_load_lds(                                          \
        (const __attribute__((address_space(1))) void*)((PTR0) + (KOFF)),      \
        (__attribute__((address_space(3))) void*)(lds + _wb), 16, 0, 0);       \
    __builtin_amdgcn_global_load_lds(                                          \
        (const __attribute__((address_space(1))) void*)((PTR1) + (KOFF)),      \
        (__attribute__((address_space(3))) void*)(lds + _wb + 8192), 16, 0, 0);\
  } while (0)

  // PHASE: M2 = mi-half (0/1), KS = k-slice (0/1); stages half (SMAT,KS) of
  // K-tile t+1 when DO_STAGE; VM: -1 none, 4 -> vmcnt(4), 0 -> vmcnt(0).
#define PHASE(M2, KS, DO_STAGE, SPTR0, SPTR1, SREG, VM) do {                   \
    short8v af[4];                                                             \
    { const char* _ab = lds + _pb + (KS) * 16384;                              \
      _Pragma("unroll")                                                        \
      for (int mi = 0; mi < 4; ++mi)                                           \
        af[mi] = *(const short8v*)(_ab + arow + ((M2) * 4 + mi) * 1024); }     \
    if ((M2) == 0) {                                                           \
      const char* _bb = lds + _pb + 32768 + (KS) * 16384;                      \
      _Pragma("unroll")                                                        \
      for (int ni = 0; ni < 4; ++ni)                                           \
        bfr[ni] = *(const short8v*)(_bb + brow + ni * 1024); }                 \
    if (DO_STAGE) { STAGE(SPTR0, SPTR1, SREG, _kbase + (KS) * 32); }           \
    if ((VM) == 4)      asm volatile("s_waitcnt vmcnt(4)" ::: "memory");       \
    else if ((VM) == 0) asm volatile("s_waitcnt vmcnt(0)" ::: "memory");       \
    __builtin_amdgcn_s_barrier();                                              \
    asm volatile("s_waitcnt lgkmcnt(0)" ::: "memory");                         \
    __builtin_amdgcn_sched_barrier(0);                                         \
    __builtin_amdgcn_s_setprio(1);                                             \
    _Pragma("unroll")                                                          \
    for (int mi = 0; mi < 4; ++mi)                                             \
      _Pragma("unroll")                                                        \
      for (int ni = 0; ni < 4; ++ni)                                           \
        acc[(M2) * 4 + mi][ni] = __builtin_amdgcn_mfma_f32_16x16x32_bf16(      \
            af[mi], bfr[ni], acc[(M2) * 4 + mi][ni], 0, 0, 0);                 \
    __builtin_amdgcn_s_setprio(0);                                             \
  } while (0)

  // prologue: stage K-tile 0 (A0,B0,A1,B1) into buf0; drain A0,B0 (leave 4)
  {
    const int _np = 0;
    STAGE(pA0, pA1, 0,     0);
    STAGE(pB0, pB1, 32768, 0);
    STAGE(pA0, pA1, 16384, 32);
    STAGE(pB0, pB1, 49152, 32);
  }
  asm volatile("s_waitcnt vmcnt(4)" ::: "memory");
  __builtin_amdgcn_s_barrier();

  // main loop: K-tiles 0..14 stage K-tile t+1
  for (int t = 0; t < 15; ++t) {
    const int _pb = (t & 1) << 16;
    const int _np = _pb ^ 65536;
    const size_t _kbase = (size_t)(t + 1) << 6;         // element col of K-tile t+1
    PHASE(0, 0, 1, pA0, pA1, 0,     -1);
    PHASE(1, 0, 1, pB0, pB1, 32768,  4);
    PHASE(0, 1, 1, pA0, pA1, 16384, -1);
    PHASE(1, 1, 1, pB0, pB1, 49152,  4);
  }
  // tail K-tile 15: no staging; drain remaining A1(15),B1(15) before ph3
  {
    const int _pb = (15 & 1) << 16;
    const int _np = 0; const size_t _kbase = 0; (void)_np; (void)_kbase;
    PHASE(0, 0, 0, pA0, pA1, 0, -1);
    PHASE(1, 0, 0, pA0, pA1, 0,  0);
    PHASE(0, 1, 0, pA0, pA1, 0, -1);
    PHASE(1, 1, 0, pA0, pA1, 0, -1);
  }
#undef PHASE
#undef STAGE

  // ---- epilogue: tanh(+hb+b1+b2) * V, row-reduce over 16 lanes, atomicAdd ----
  const int b = row0 >> 10;                 // 256-row tile never crosses batch
  float vv[4], hbv[4];
#pragma unroll
  for (int ni = 0; ni < 4; ++ni) {
    int col = n0 + (wn << 6) + (ni << 4) + r16;
    vv[ni]  = Vv[col];
    hbv[ni] = hb[(b << 10) + col] + b1[col] + b2[col];
  }
  float rowsum[8][4];
#pragma unroll
  for (int mi = 0; mi < 8; ++mi)
#pragma unroll
    for (int j = 0; j < 4; ++j) rowsum[mi][j] = 0.0f;
#pragma unroll
  for (int mi = 0; mi < 8; ++mi)
#pragma unroll
    for (int ni = 0; ni < 4; ++ni)
#pragma unroll
      for (int j = 0; j < 4; ++j)
        rowsum[mi][j] += fast_tanh(acc[mi][ni][j] + hbv[ni]) * vv[ni];
#pragma unroll
  for (int mi = 0; mi < 8; ++mi)
#pragma unroll
    for (int j = 0; j < 4; ++j) {
      float rs = rowsum[mi][j];
      rs += __shfl_xor(rs, 1);
      rs += __shfl_xor(rs, 2);
      rs += __shfl_xor(rs, 4);
      rs += __shfl_xor(rs, 8);
      if (r16 == 0)
        atomicAdd(score + row0 + (wm << 7) + (mi << 4) + (g4 << 2) + j, rs);
    }
}

// ---------------- fallback fp32-input score GEMM (path B only) ----------------
__global__ __launch_bounds__(256) void score_gemm_f32_k(
    const float* __restrict__ encf, const u16* __restrict__ w1t,
    const float* __restrict__ hb, const float* __restrict__ b1,
    const float* __restrict__ b2, const float* __restrict__ Vv,
    float* __restrict__ score)
{
  __shared__ __align__(16) char lds[32768];
  const int tid  = threadIdx.x;
  const int lane = tid & 63;
  const int wid  = tid >> 6;
  const int wm = wid >> 1, wn = wid & 1;
  const int r16 = lane & 15, g4 = lane >> 4;
  int bid = blockIdx.x;
  int logical = (bid & 7) * 1024 + (bid >> 3);
  const int row0 = (logical >> 3) << 7;
  const int n0   = (logical & 7) << 7;
  f32x4 acc[4][4] = {};
  for (int kk = 0; kk < U_; kk += 64) {
#pragma unroll
    for (int qi = 0; qi < 4; ++qi) {
      int q = 16 + wid * 4 + qi;
      int n = ((q - 16) << 3) + (lane >> 3);
      int c = lane & 7;
      int j = c ^ (n & 7);
      const u16* src = w1t + (((size_t)(n0 + n)) << 10) + kk + (j << 3);
      __builtin_amdgcn_global_load_lds(
          (const __attribute__((address_space(1))) void*)src,
          (__attribute__((address_space(3))) void*)(lds + (q << 10)), 16, 0, 0);
    }
#pragma unroll
    for (int i = 0; i < 4; ++i) {
      int cg = tid * 4 + i;
      int r = cg >> 3, c = cg & 7;
      int j = c ^ (r & 7);
      const float* g = encf + (((size_t)(row0 + r)) << 10) + kk + (j << 3);
      float4 a = *(const float4*)g;
      float4 b = *(const float4*)(g + 4);
      *(short8v*)(lds + (cg << 4)) = pack8(a, b);
    }
    __syncthreads();
#pragma unroll
    for (int ks = 0; ks < 2; ++ks) {
      short8v af[4], bf[4];
#pragma unroll
      for (int mi = 0; mi < 4; ++mi) {
        int row = (wm << 6) + (mi << 4) + r16;
        int jx = (ks << 2) + g4;
        af[mi] = *(const short8v*)(lds + (row << 7) + ((jx ^ (row & 7)) << 4));
      }
#pragma unroll
      for (int ni = 0; ni < 4; ++ni) {
        int n = (wn << 6) + (ni << 4) + r16;
        int jx = (ks << 2) + g4;
        bf[ni] = *(const short8v*)(lds + 16384 + (n << 7) + ((jx ^ (n & 7)) << 4));
      }
#pragma unroll
      for (int mi = 0; mi < 4; ++mi)
#pragma unroll
        for (int ni = 0; ni < 4; ++ni)
          acc[mi][ni] = __builtin_amdgcn_mfma_f32_16x16x32_bf16(af[mi], bf[ni], acc[mi][ni], 0, 0, 0);
    }
    __syncthreads();
  }
  const int b = row0 >> 10;
  float vv[4], hbv[4];
#pragma unroll
  for (int ni = 0; ni < 4; ++ni) {
    int col = n0 + (wn << 6) + (ni << 4) + r16;
    vv[ni]  = Vv[col];
    hbv[ni] = hb[(b << 10) + col] + b1[col] + b2[col];
  }
  float rowsum[4][4];
#pragma unroll
  for (int mi = 0; mi < 4; ++mi)
#pragma unroll
    for (int j = 0; j < 4; ++j) rowsum[mi][j] = 0.0f;
#pragma unroll
  for (int mi = 0; mi < 4; ++mi)
#pragma unroll
    for (int ni = 0; ni < 4; ++ni)
#pragma unroll
      for (int j = 0; j < 4; ++j)
        rowsum[mi][j] += fast_tanh(acc[mi][ni][j] + hbv[ni]) * vv[ni];
#pragma unroll
  for (int mi = 0; mi < 4; ++mi)
#pragma unroll
    for (int j = 0; j < 4; ++j) {
      float rs = rowsum[mi][j];
      rs += __shfl_xor(rs, 1);
      rs += __shfl_xor(rs, 2);
      rs += __shfl_xor(rs, 4);
      rs += __shfl_xor(rs, 8);
      if (r16 == 0)
        atomicAdd(score + row0 + (wm << 6) + (mi << 4) + (g4 << 2) + j, rs);
    }
}

// ---------------- fused softmax (blocks 0..127) + ginx (128..159) ----------
__global__ void sm_ginx_k(const float* __restrict__ score, float* __restrict__ attn,
                          const float* __restrict__ x, float* __restrict__ gin) {
  if (blockIdx.x < 128) {
    __shared__ float red[8];
    int b = blockIdx.x, t = threadIdx.x;     // 256 threads, 4 vals each
    float4 v = ((const float4*)(score + ((size_t)b << 10)))[t];
    float m = fmaxf(fmaxf(v.x, v.y), fmaxf(v.z, v.w));
    for (int o = 1; o < 64; o <<= 1) m = fmaxf(m, __shfl_xor(m, o));
    if ((t & 63) == 0) red[t >> 6] = m;
    __syncthreads();
    m = fmaxf(fmaxf(red[0], red[1]), fmaxf(red[2], red[3]));
    float e0 = expf(v.x - m), e1 = expf(v.y - m), e2 = expf(v.z - m), e3 = expf(v.w - m);
    float s = e0 + e1 + e2 + e3;
    for (int o = 1; o < 64; o <<= 1) s += __shfl_xor(s, o);
    if ((t & 63) == 0) red[4 + (t >> 6)] = s;
    __syncthreads();
    s = red[4] + red[5] + red[6] + red[7];
    float inv = 1.0f / s;
    float4 o4; o4.x = e0 * inv; o4.y = e1 * inv; o4.z = e2 * inv; o4.w = e3 * inv;
    ((float4*)(attn + ((size_t)b << 10)))[t] = o4;
  } else {
    int i = (blockIdx.x - 128) * 256 + threadIdx.x;   // 8192
    int b = i >> 6, c = i & 63;
    gin[(size_t)b * 1088 + 1024 + c] = x[i];
  }
}

// ---------------- context = attn^T @ enc  (accumulate into gin[:, :1024]) ----------------
template<bool ABF16>
__global__ void context_k(const void* __restrict__ encp, const float* __restrict__ attn,
                          float* __restrict__ gin) {
  __shared__ float aw[128];
  int b = blockIdx.x >> 3, sc = blockIdx.x & 7, t = threadIdx.x;
  if (t < 128) aw[t] = attn[((size_t)b << 10) + sc * 128 + t];
  __syncthreads();
  float a0 = 0.f, a1 = 0.f, a2 = 0.f, a3 = 0.f;
  size_t base = ((size_t)b << 20) + ((size_t)(sc * 128) << 10);
  for (int s = 0; s < 128; ++s) {
    float w = aw[s];
    if (ABF16) {
      ushort4 e = *(const ushort4*)((const u16*)encp + base + ((size_t)s << 10) + t * 4);
      a0 += w * bf2f(e.x); a1 += w * bf2f(e.y); a2 += w * bf2f(e.z); a3 += w * bf2f(e.w);
    } else {
      float4 e = *(const float4*)((const float*)encp + base + ((size_t)s << 10) + t * 4);
      a0 += w * e.x; a1 += w * e.y; a2 += w * e.z; a3 += w * e.w;
    }
  }
  float* g = gin + (size_t)b * 1088 + t * 4;
  atomicAdd(g + 0, a0); atomicAdd(g + 1, a1); atomicAdd(g + 2, a2); atomicAdd(g + 3, a3);
}

// ---------------- split-K fp32 GEMM body: C += A@W (partial, atomic) --------
__device__ __forceinline__ void splitk_body(
    const float* __restrict__ A, int lda,
    const float* __restrict__ W, int ldw,
    float* __restrict__ C, int ldc, int m0, int n0, int k0)
{
  __shared__ float As[64][68];
  __shared__ float Bs[64][64];
  int t = threadIdx.x;
#pragma unroll
  for (int q = 0; q < 4; ++q) {            // A: 64 rows x 16 float4
    int cidx = q * 256 + t;
    int m = cidx >> 4, c4 = cidx & 15;
    float4 v = *(const float4*)(A + (size_t)(m0 + m) * lda + k0 + (c4 << 2));
    As[m][(c4 << 2) + 0] = v.x; As[m][(c4 << 2) + 1] = v.y;
    As[m][(c4 << 2) + 2] = v.z; As[m][(c4 << 2) + 3] = v.w;
  }
#pragma unroll
  for (int q = 0; q < 4; ++q) {            // B: 64 k-rows x 16 float4
    int cidx = q * 256 + t;
    int k = cidx >> 4, nn = cidx & 15;
    *(float4*)&Bs[k][nn << 2] =
        *(const float4*)(W + (size_t)(k0 + k) * ldw + n0 + (nn << 2));
  }
  __syncthreads();
  int tx = t & 15, ty = t >> 4;
  float acc[4][4] = {};
#pragma unroll 8
  for (int k = 0; k < 64; ++k) {
    float a0 = As[(ty << 2) + 0][k], a1 = As[(ty << 2) + 1][k];
    float a2 = As[(ty << 2) + 2][k], a3 = As[(ty << 2) + 3][k];
    float4 bv = *(const float4*)&Bs[k][tx << 2];
    acc[0][0] += a0 * bv.x; acc[0][1] += a0 * bv.y; acc[0][2] += a0 * bv.z; acc[0][3] += a0 * bv.w;
    acc[1][0] += a1 * bv.x; acc[1][1] += a1 * bv.y; acc[1][2] += a1 * bv.z; acc[1][3] += a1 * bv.w;
    acc[2][0] += a2 * bv.x; acc[2][1] += a2 * bv.y; acc[2][2] += a2 * bv.z; acc[2][3] += a2 * bv.w;
    acc[3][0] += a3 * bv.x; acc[3][1] += a3 * bv.y; acc[3][2] += a3 * bv.z; acc[3][3] += a3 * bv.w;
  }
  int col = n0 + (tx << 2);
#pragma unroll
  for (int i = 0; i < 4; ++i) {
    int row = m0 + (ty << 2) + i;
#pragma unroll
    for (int j = 0; j < 4; ++j)
      atomicAdd(C + (size_t)row * ldc + col + j, acc[i][j]);
  }
}

__global__ __launch_bounds__(256) void gemm_splitk_k(
    const float* __restrict__ A, int lda,
    const float* __restrict__ W, int ldw,
    float* __restrict__ C, int ldc)
{
  splitk_body(A, lda, W, ldw, C, ldc,
              blockIdx.x << 6, blockIdx.y << 6, blockIdx.z << 6);
}

// ---------------- fused GRU input GEMMs: xg (0..1631) + hr (1632..2655) ------
// xg = gin@Wk (128x3072, K=1088: 2x48x17 flattened); hr = hidden@Wr[:, :2048]
// (128x2048, K=1024: 2x32x16 flattened). Independent -> one launch.
__global__ __launch_bounds__(256) void gru2_k(
    const float* __restrict__ gin, const float* __restrict__ Wk,
    float* __restrict__ xg, const float* __restrict__ hid,
    const float* __restrict__ Wr, float* __restrict__ hr)
{
  int bx = blockIdx.x;
  if (bx < 1632) {
    int m0 = (bx & 1) << 6; int q = bx >> 1;          // q in [0,816)
    int n0 = (q % 48) << 6; int k0 = (q / 48) << 6;   // n<48, k<17
    splitk_body(gin, 1088, Wk, 3072, xg, 3072, m0, n0, k0);
  } else {
    int sub = bx - 1632;
    int m0 = (sub & 1) << 6; int q = sub >> 1;        // q in [0,512)
    int n0 = (q % 32) << 6; int k0 = (q / 32) << 6;   // n<32, k<16
    splitk_body(hid, 1024, Wr, 3072, hr, 2048, m0, n0, k0);
  }
}

// ---------------- GRU elementwise epilogues ----------------
__global__ void zr_k(const float* __restrict__ xg, const float* __restrict__ hr,
                     const float* __restrict__ hid, const float* __restrict__ bg,
                     float* __restrict__ z, float* __restrict__ rh) {
  int i = blockIdx.x * 256 + threadIdx.x;   // 131072
  int b = i >> 10, n = i & 1023;
  float zv = xg[(size_t)b * 3072 + n] + bg[n] + hr[(size_t)b * 2048 + n];
  float rv = xg[(size_t)b * 3072 + 1024 + n] + bg[1024 + n] + hr[(size_t)b * 2048 + 1024 + n];
  zv = 1.0f / (1.0f + expf(-zv));
  rv = 1.0f / (1.0f + expf(-rv));
  z[i] = zv;
  rh[i] = rv * hid[i];
}

__global__ void state_ep_k(const float* __restrict__ hh, const float* __restrict__ xg,
                           const float* __restrict__ bg, const float* __restrict__ z,
                           const float* __restrict__ hid, float* __restrict__ state) {
  int i = blockIdx.x * 256 + threadIdx.x;   // 131072
  int b = i >> 10, n = i & 1023;
  float val = hh[i] + xg[(size_t)b * 3072 + 2048 + n] + bg[2048 + n];
  float th = tanhf(val);
  float zv = z[i];
  state[i] = zv * hid[i] + (1.0f - zv) * th;
}

__global__ void out_ep_k(float* __restrict__ out, const float* __restrict__ bfc) {
  int i = blockIdx.x * 256 + threadIdx.x;   // 8192
  out[i] += bfc[i & 63];
}

extern "C" void kernel_launch(void* const* d_in, const int* in_sizes, int n_in,
                              void* d_out, int out_size, void* d_ws, size_t ws_size,
                              hipStream_t stream) {
  const float* x    = (const float*)d_in[0];
  const float* hid  = (const float*)d_in[1];
  const float* enc  = (const float*)d_in[2];
  const float* W1   = (const float*)d_in[3];
  const float* b1   = (const float*)d_in[4];
  const float* W2   = (const float*)d_in[5];
  const float* b2   = (const float*)d_in[6];
  const float* Vv   = (const float*)d_in[7];
  // d_in[8] = bV: softmax shift-invariant -> unused
  const float* Wk   = (const float*)d_in[9];
  const float* Wr   = (const float*)d_in[10];
  const float* bg   = (const float*)d_in[11];
  const float* Wfc  = (const float*)d_in[12];
  const float* bfc  = (const float*)d_in[13];

  float* out       = (float*)d_out;
  float* state_out = out + 8192;
  float* attn_out  = out + 8192 + 131072;

  char* ws = (char*)d_ws;
  u16*   w1t   = (u16*)(ws + 0);          // 2 MB
  // --- contiguous atomic-accumulator region (one memset) ---
  float* hb    = (float*)(ws + 2097152);  // 512 KB
  float* score = (float*)(ws + 2621440);  // 512 KB
  float* gin   = (float*)(ws + 3145728);  // 128*1088*4 = 544 KB
  float* xg    = (float*)(ws + 3702784);  // 1.5 MB
  float* hr    = (float*)(ws + 5275648);  // 1 MB
  float* hh    = (float*)(ws + 6324224);  // 512 KB
  // --- non-accumulated ---
  float* z     = (float*)(ws + 6848512);  // 512 KB
  float* rh    = (float*)(ws + 7372800);  // 512 KB
  u16*   enc16 = (u16*)(ws + 8388608);    // 256 MB (path A only)
  const bool pathA = ws_size >= (8388608ULL + 268435456ULL);

  hipMemsetAsync(ws + 2097152, 0, 6848512 - 2097152, stream);  // hb..hh
  hipMemsetAsync(out, 0, 32768, stream);                       // fc accumulator

  // fused prep: conv_w1t (1024 blocks) + conv_enc (4096 blocks, path A)
  prep_k<<<pathA ? 5120 : 1024, 256, 0, stream>>>(W1, w1t, enc,
                                                  pathA ? enc16 : nullptr);

  // hb = hidden@W2 (biases folded into score epilogue)
  gemm_splitk_k<<<dim3(2, 16, 16), 256, 0, stream>>>(hid, 1024, W2, 1024, hb, 1024);

  if (pathA)
    score_gemm2_k<<<2048, 512, 0, stream>>>(enc16, w1t, hb, b1, b2, Vv, score);
  else
    score_gemm_f32_k<<<8192, 256, 0, stream>>>(enc, w1t, hb, b1, b2, Vv, score);

  sm_ginx_k<<<160, 256, 0, stream>>>(score, attn_out, x, gin);

  if (pathA) context_k<true><<<1024, 256, 0, stream>>>(enc16, attn_out, gin);
  else       context_k<false><<<1024, 256, 0, stream>>>(enc, attn_out, gin);

  // fused xg = gin@Wk and hr = hidden@Wr[:, :2048]
  gru2_k<<<2656, 256, 0, stream>>>(gin, Wk, xg, hid, Wr, hr);
  zr_k<<<512, 256, 0, stream>>>(xg, hr, hid, bg, z, rh);
  // hh = (r*h)@Wr[:, 2U:]
  gemm_splitk_k<<<dim3(2, 16, 16), 256, 0, stream>>>(rh, 1024, Wr + 2048, 3072, hh, 1024);
  state_ep_k<<<512, 256, 0, stream>>>(hh, xg, bg, z, hid, state_out);
  // out = state@Wfc + bfc
  gemm_splitk_k<<<dim3(2, 1, 16), 256, 0, stream>>>(state_out, 1024, Wfc, 64, out, 64);
  out_ep_k<<<32, 256, 0, stream>>>(out, bfc);
}